// Round 1
// baseline (1063.388 us; speedup 1.0000x reference)
//
#include <hip/hip_runtime.h>
#include <math.h>

#define NLEVEL 16
#define TSIZE 16384

using half4 = __attribute__((ext_vector_type(4))) _Float16;
using f32x4 = __attribute__((ext_vector_type(4))) float;
using f32x2 = __attribute__((ext_vector_type(2))) float;

struct NsParam { int n[NLEVEL]; unsigned densemask; };

union Frag { half4 v; int i[2]; };

// A-fragment for mfma_f32_16x16x16f16 of W^T (W row-major [K][N] fp32):
// lane (pt=lane&15, q=lane>>4) holds A[m=out][k=k0+4q+j], j=0..3.
__device__ __forceinline__ Frag load_wfrag(const float* __restrict__ W, int ldn,
                                           int k0, int q, int out,
                                           int kmax, int omax) {
    Frag f;
    #pragma unroll
    for (int j = 0; j < 4; ++j) {
        int k = k0 + 4 * q + j;
        float v = (k < kmax && out < omax) ? W[k * ldn + out] : 0.0f;
        f.v[j] = (_Float16)v;
    }
    return f;
}

__device__ __forceinline__ f32x4 mfma16(const Frag& a, const Frag& b, f32x4 c) {
    return __builtin_amdgcn_mfma_f32_16x16x16f16(a.v, b.v, c, 0, 0, 0);
}

// relu + cvt: C-tile f32x4 -> B-fragment half4 (layouts match for K=16!)
__device__ __forceinline__ Frag actpack(f32x4 a) {
    Frag f;
    #pragma unroll
    for (int j = 0; j < 4; ++j) f.v[j] = (_Float16)fmaxf(a[j], 0.0f);
    return f;
}

__device__ __forceinline__ float sigmoidf(float x) {
    return 1.0f / (1.0f + expf(-x));
}

// q-select among 4 values (q = lane>>4)
__device__ __forceinline__ int qsel(int q, int a, int b, int c, int d) {
    return (q & 2) ? ((q & 1) ? d : c) : ((q & 1) ? b : a);
}

// Compute hash/dense addresses for 4 levels x 8 corners and ISSUE all 32
// gathers back-to-back (fe = 64 VGPRs of in-flight destinations).
// Interpolation weights are stashed in w_ for later consumption.
__device__ __forceinline__ void enc_issue(
    float px, float py, float pz,
    const float fn_[4], const float* const eb_[4],
    const int np1_[4], const int np1sq_[4], const bool dense_[4],
    f32x2 fe[4][8], float w_[4][3])
{
    float cx = fminf(fmaxf((px + 5.0f) / 10.0f, 0.0f), 0.999999f);
    float cy = fminf(fmaxf((py + 5.0f) / 10.0f, 0.0f), 0.999999f);
    float cz = fminf(fmaxf((pz + 5.0f) / 10.0f, 0.0f), 0.999999f);

    #pragma unroll
    for (int d = 0; d < 4; ++d) {
        float fn = fn_[d];
        float xl0 = cx * fn, xl1 = cy * fn, xl2 = cz * fn;
        float f0 = floorf(xl0), f1 = floorf(xl1), f2 = floorf(xl2);
        int i0 = (int)f0, i1 = (int)f1, i2 = (int)f2;
        w_[d][0] = xl0 - f0; w_[d][1] = xl1 - f1; w_[d][2] = xl2 - f2;

        unsigned hx0 = (unsigned)i0, hx1 = hx0 + 1u;
        unsigned hy0 = (unsigned)i1 * 2654435761u, hy1 = hy0 + 2654435761u;
        unsigned hz0 = (unsigned)i2 * 805459861u,  hz1 = hz0 + 805459861u;
        int dx0 = 0, dx1 = 0, dy0 = 0, dy1 = 0;
        if (d < 2) {  // only levels 0,1 can be dense
            dx0 = i0 * np1sq_[d]; dx1 = dx0 + np1sq_[d];
            dy0 = i1 * np1_[d];   dy1 = dy0 + np1_[d];
        }
        #pragma unroll
        for (int c = 0; c < 8; ++c) {
            int o0 = (c >> 2) & 1, o1 = (c >> 1) & 1, o2 = c & 1;
            unsigned h = (o0 ? hx1 : hx0) ^ (o1 ? hy1 : hy0) ^ (o2 ? hz1 : hz0);
            int ind = (int)(h & (TSIZE - 1));
            if (d < 2) {
                int di = (o0 ? dx1 : dx0) + (o1 ? dy1 : dy0) + i2 + o2;
                ind = dense_[d] ? di : ind;
            }
            fe[d][c] = *(const f32x2*)(eb_[d] + (size_t)ind * 2);
        }
    }
}

// One wave = 16 points. Lane (pt, q). All layers via 16x16x16 f16 MFMA.
// Weights/biases live in LDS (frees ~80 VGPRs -> all 32 embed gathers of a
// tile stay in flight); gathers for tile t+1 are issued BEFORE the MLP of
// tile t so the full MFMA/VALU phase overlaps the L2 gather latency.
__global__ __launch_bounds__(256) void nerf_mfma(
    const float* __restrict__ x,
    const float* __restrict__ embed,
    const float* __restrict__ dW0, const float* __restrict__ db0,
    const float* __restrict__ dW1, const float* __restrict__ db1,
    const float* __restrict__ cW0, const float* __restrict__ cb0,
    const float* __restrict__ cW1, const float* __restrict__ cb1,
    const float* __restrict__ cW2, const float* __restrict__ cb2,
    float* __restrict__ out, int B, NsParam ns)
{
    const int lane = threadIdx.x & 63;
    const int pt = lane & 15;
    const int q  = lane >> 4;

    // ---- LDS-resident weight fragments + bias/acc-init vectors ----
    // frag table: [0..7]=dW0(t*2+c) [8..11]=dW1(c) [12..19]=cW0 [20..35]=cW1 [36..39]=cW2
    __shared__ Frag wlds[40][64];
    // bias table: [0..3]=db0(t) [4]=db1 [5..8]=cb0(t) [9..12]=cb1(t) [13]=cb2-init
    __shared__ f32x4 blds[14][64];

    for (int i = threadIdx.x; i < 40 * 64; i += blockDim.x) {
        int f = i >> 6, ln = i & 63;
        int fq = ln >> 4, fpt = ln & 15;
        Frag fr;
        if (f < 8)       fr = load_wfrag(dW0, 64, 16 * (f & 1), fq, 16 * (f >> 1) + fpt, 32, 64);
        else if (f < 12) fr = load_wfrag(dW1, 16, 16 * (f - 8), fq, fpt, 64, 16);
        else if (f < 20) fr = load_wfrag(cW0, 64, 16 * ((f - 12) & 1), fq, 16 * ((f - 12) >> 1) + fpt, 19, 64);
        else if (f < 36) fr = load_wfrag(cW1, 64, 16 * ((f - 20) & 3), fq, 16 * ((f - 20) >> 2) + fpt, 64, 64);
        else             fr = load_wfrag(cW2, 3, 16 * (f - 36), fq, fpt, 64, 3);
        wlds[f][ln] = fr;
    }
    for (int i = threadIdx.x; i < 14 * 64; i += blockDim.x) {
        int f = i >> 6, ln = i & 63;
        int fq = ln >> 4;
        f32x4 v;
        if (f < 4) {
            #pragma unroll
            for (int j = 0; j < 4; ++j) v[j] = db0[16 * f + 4 * fq + j];
        } else if (f == 4) {
            #pragma unroll
            for (int j = 0; j < 4; ++j) v[j] = db1[4 * fq + j];
        } else if (f < 9) {
            #pragma unroll
            for (int j = 0; j < 4; ++j) v[j] = cb0[16 * (f - 5) + 4 * fq + j];
        } else if (f < 13) {
            #pragma unroll
            for (int j = 0; j < 4; ++j) v[j] = cb1[16 * (f - 9) + 4 * fq + j];
        } else {
            v[0] = (fq == 0) ? cb2[0] : 0.0f;
            v[1] = (fq == 0) ? cb2[1] : 0.0f;
            v[2] = (fq == 0) ? cb2[2] : 0.0f;
            v[3] = 0.0f;
        }
        blds[f][ln] = v;
    }
    __syncthreads();

    const int wavesPerBlock = blockDim.x >> 6;
    const int waveId = blockIdx.x * wavesPerBlock + (threadIdx.x >> 6);
    const int waveStride = gridDim.x * wavesPerBlock;
    const int numTiles = B >> 4;

    // ---- per-lane encode level state (fixed across tiles) ----
    // This lane computes levels {2q, 2q+1, 8+2q, 9+2q} = d 0..3.
    float fn_[4];
    const float* eb_[4];
    int np1_[4], np1sq_[4];
    bool dense_[4];
    #pragma unroll
    for (int d = 0; d < 4; ++d) {
        int base = (d < 2) ? (d) : (8 + (d - 2));   // level = base + 2q
        int lvl = base + 2 * q;
        int n = qsel(q, ns.n[base], ns.n[base + 2], ns.n[base + 4], ns.n[base + 6]);
        fn_[d] = (float)n;
        np1_[d] = n + 1;
        np1sq_[d] = (n + 1) * (n + 1);
        dense_[d] = (ns.densemask >> lvl) & 1u;
        eb_[d] = embed + (size_t)lvl * (TSIZE * 2);
    }

    int tile = waveId;
    if (tile >= numTiles) return;

    f32x2 fe[4][8];     // 64 VGPRs of in-flight gather destinations
    float w_[4][3];
    float vx, vy, vz;

    // ---- prologue: issue gathers for the first tile ----
    {
        const float* xp = x + (size_t)(tile * 16 + pt) * 6;
        f32x2 a01 = __builtin_nontemporal_load((const f32x2*)xp);
        f32x2 a23 = __builtin_nontemporal_load((const f32x2*)(xp + 2));
        f32x2 a45 = __builtin_nontemporal_load((const f32x2*)(xp + 4));
        vx = a23.y; vy = a45.x; vz = a45.y;
        enc_issue(a01.x, a01.y, a23.x, fn_, eb_, np1_, np1sq_, dense_, fe, w_);
    }

    for (;;) {
        int next = tile + waveStride;
        bool hasNext = next < numTiles;

        // prefetch next tile's x early (coalesced, nontemporal)
        f32x2 n01, n23, n45;
        if (hasNext) {
            const float* xp = x + (size_t)(next * 16 + pt) * 6;
            n01 = __builtin_nontemporal_load((const f32x2*)xp);
            n23 = __builtin_nontemporal_load((const f32x2*)(xp + 2));
            n45 = __builtin_nontemporal_load((const f32x2*)(xp + 4));
        }

        // ---- interpolate current tile's features -> B-frags (fe dies here) ----
        Frag bf0, bf1;
        #pragma unroll
        for (int d = 0; d < 4; ++d) {
            float w0 = w_[d][0], w1 = w_[d][1], w2 = w_[d][2];
            float u0 = 1.0f - w0, u1 = 1.0f - w1, u2 = 1.0f - w2;
            float wxy[4] = { u0 * u1, u0 * w1, w0 * u1, w0 * w1 };
            float a0 = 0.0f, a1 = 0.0f;
            #pragma unroll
            for (int c = 0; c < 8; ++c) {
                float ww = wxy[c >> 1] * ((c & 1) ? w2 : u2);
                a0 = fmaf(fe[d][c].x, ww, a0);
                a1 = fmaf(fe[d][c].y, ww, a1);
            }
            if (d == 0)      { bf0.v[0] = (_Float16)a0; bf0.v[1] = (_Float16)a1; }
            else if (d == 1) { bf0.v[2] = (_Float16)a0; bf0.v[3] = (_Float16)a1; }
            else if (d == 2) { bf1.v[0] = (_Float16)a0; bf1.v[1] = (_Float16)a1; }
            else             { bf1.v[2] = (_Float16)a0; bf1.v[3] = (_Float16)a1; }
        }

        // stash current view dir, then issue NEXT tile's 32 gathers so they
        // are in flight for the entire MLP below (T14 async-split).
        float cvx = vx, cvy = vy, cvz = vz;
        if (hasNext) {
            vx = n23.y; vy = n45.x; vz = n45.y;
            enc_issue(n01.x, n01.y, n23.x, fn_, eb_, np1_, np1sq_, dense_, fe, w_);
        }

        // ---- MLP for current tile (weights/biases from LDS) ----
        // fresh opaque lane index each iteration: defeats LICM re-hoisting
        // the loop-invariant LDS reads into permanently-live VGPRs.
        int wl = lane;
        asm("" : "+v"(wl));

        // L0: h64 = dW0^T @ feats (4 out-tiles, K=32)
        f32x4 acc[4];
        #pragma unroll
        for (int t = 0; t < 4; ++t) {
            acc[t] = blds[t][wl];
            acc[t] = mfma16(wlds[2 * t + 0][wl], bf0, acc[t]);
            acc[t] = mfma16(wlds[2 * t + 1][wl], bf1, acc[t]);
        }
        Frag bh[4];
        #pragma unroll
        for (int c = 0; c < 4; ++c) bh[c] = actpack(acc[c]);

        // L1: h16 = dW1^T @ relu(h64) (1 tile, K=64)
        f32x4 h = blds[4][wl];
        #pragma unroll
        for (int c = 0; c < 4; ++c) h = mfma16(wlds[8 + c][wl], bh[c], h);

        float dens = sigmoidf(h[0]);            // row 0 lives at q==0, reg 0
        Frag bcin0, bcin1;
        {
            float a0v = (q == 0) ? dens : fmaxf(h[0], 0.0f);
            bcin0.v[0] = (_Float16)a0v;
            bcin0.v[1] = (_Float16)fmaxf(h[1], 0.0f);
            bcin0.v[2] = (_Float16)fmaxf(h[2], 0.0f);
            bcin0.v[3] = (_Float16)fmaxf(h[3], 0.0f);
            // k=16+4q+j: q==0 holds k16..19 = (vx,vy,vz,0) of its own point
            bcin1.v[0] = (_Float16)((q == 0) ? cvx : 0.0f);
            bcin1.v[1] = (_Float16)((q == 0) ? cvy : 0.0f);
            bcin1.v[2] = (_Float16)((q == 0) ? cvz : 0.0f);
            bcin1.v[3] = (_Float16)0.0f;
        }

        // L2: c1 = cW0^T @ cin (4 out-tiles, K=19 padded to 32)
        #pragma unroll
        for (int t = 0; t < 4; ++t) {
            acc[t] = blds[5 + t][wl];
            acc[t] = mfma16(wlds[12 + 2 * t + 0][wl], bcin0, acc[t]);
            acc[t] = mfma16(wlds[12 + 2 * t + 1][wl], bcin1, acc[t]);
        }
        Frag bc[4];
        #pragma unroll
        for (int c = 0; c < 4; ++c) bc[c] = actpack(acc[c]);

        // L3: c2 = cW1^T @ relu(c1) (4 out-tiles, K=64)
        #pragma unroll
        for (int t = 0; t < 4; ++t) {
            acc[t] = blds[9 + t][wl];
            #pragma unroll
            for (int c = 0; c < 4; ++c)
                acc[t] = mfma16(wlds[20 + 4 * t + c][wl], bc[c], acc[t]);
        }
        Frag bd[4];
        #pragma unroll
        for (int c = 0; c < 4; ++c) bd[c] = actpack(acc[c]);

        // L4: col = cW2^T @ relu(c2) (rows 0..2, K=64)
        f32x4 fo = blds[13][wl];
        #pragma unroll
        for (int c = 0; c < 4; ++c) fo = mfma16(wlds[36 + c][wl], bd[c], fo);

        if (q == 0) {
            f32x4 o;
            o[0] = dens;
            o[1] = sigmoidf(fo[0]);
            o[2] = sigmoidf(fo[1]);
            o[3] = sigmoidf(fo[2]);
            __builtin_nontemporal_store(o, (f32x4*)(out + (size_t)(tile * 16 + pt) * 4));
        }

        if (!hasNext) break;
        tile = next;
    }
}

extern "C" void kernel_launch(void* const* d_in, const int* in_sizes, int n_in,
                              void* d_out, int out_size, void* d_ws, size_t ws_size,
                              hipStream_t stream) {
    const float* x    = (const float*)d_in[0];
    const float* embed= (const float*)d_in[1];
    const float* dW0  = (const float*)d_in[2];
    const float* db0  = (const float*)d_in[3];
    const float* dW1  = (const float*)d_in[4];
    const float* db1  = (const float*)d_in[5];
    const float* cW0  = (const float*)d_in[6];
    const float* cb0  = (const float*)d_in[7];
    const float* cW1  = (const float*)d_in[8];
    const float* cb1  = (const float*)d_in[9];
    const float* cW2  = (const float*)d_in[10];
    const float* cb2  = (const float*)d_in[11];
    float* out = (float*)d_out;

    int B = in_sizes[0] / 6;

    // Replicate numpy's NS computation bit-for-bit (same libm on this host).
    NsParam ns;
    double g = exp((log(512.0) - log(16.0)) / 15.0);
    ns.densemask = 0;
    for (int i = 0; i < NLEVEL; ++i) {
        ns.n[i] = (int)(16.0 * pow(g, (double)i));
        long long np1 = ns.n[i] + 1;
        if (np1 * np1 * np1 <= TSIZE) ns.densemask |= (1u << i);
    }

    int block = 256;
    int grid = 2048;   // 8192 waves, 16 tiles/wave at B=2M
    nerf_mfma<<<grid, block, 0, stream>>>(x, embed,
        dW0, db0, dW1, db1, cW0, cb0, cW1, cb1, cW2, cb2,
        out, B, ns);
}

// Round 2
// 378.703 us; speedup vs baseline: 2.8080x; 2.8080x over previous
//
#include <hip/hip_runtime.h>
#include <math.h>

#define NLEVEL 16
#define TSIZE 16384
#define CHUNK 8192   // points per encode block

using half4 = __attribute__((ext_vector_type(4))) _Float16;
using f32x4 = __attribute__((ext_vector_type(4))) float;
using f32x2 = __attribute__((ext_vector_type(2))) float;

struct NsParam { int n[NLEVEL]; unsigned densemask; };

union Frag { half4 v; int i[2]; };

// Block loop-invariant code motion from hoisting per-tile bias loads into
// permanently-live VGPRs: make the pointer "new" every iteration.
__device__ __forceinline__ void opaque(const float*& p) {
    asm("" : "+v"(p));
}

// A-fragment for mfma_f32_16x16x16f16 of W^T (W row-major [K][N] fp32):
// lane (pt=lane&15, q=lane>>4) holds A[m=out][k=k0+4q+j], j=0..3.
__device__ __forceinline__ Frag load_wfrag(const float* __restrict__ W, int ldn,
                                           int k0, int q, int out,
                                           int kmax, int omax) {
    Frag f;
    #pragma unroll
    for (int j = 0; j < 4; ++j) {
        int k = k0 + 4 * q + j;
        float v = (k < kmax && out < omax) ? W[k * ldn + out] : 0.0f;
        f.v[j] = (_Float16)v;
    }
    return f;
}

__device__ __forceinline__ f32x4 mfma16(const Frag& a, const Frag& b, f32x4 c) {
    return __builtin_amdgcn_mfma_f32_16x16x16f16(a.v, b.v, c, 0, 0, 0);
}

// relu + cvt: C-tile f32x4 -> B-fragment half4 (layouts match for K=16!)
__device__ __forceinline__ Frag actpack(f32x4 a) {
    Frag f;
    #pragma unroll
    for (int j = 0; j < 4; ++j) f.v[j] = (_Float16)fmaxf(a[j], 0.0f);
    return f;
}

__device__ __forceinline__ float sigmoidf(float x) {
    return 1.0f / (1.0f + expf(-x));
}

// q-select among 4 values (q = lane>>4)
__device__ __forceinline__ int qsel(int q, int a, int b, int c, int d) {
    return (q & 2) ? ((q & 1) ? d : c) : ((q & 1) ? b : a);
}

// ============================================================================
// Phase A: hash-grid encode with the level table staged in LDS.
// Rationale: the fused kernel is bound by the L2 random-gather REQUEST RATE
// (268M 8B line-requests ~= 875us floor). LDS serves a wave's 64 random 8B
// reads in ~8 cycles (bank-limited) instead of ~64+ via TCP/L2.
// Each block owns CHUNK points and loops over all 16 levels, staging each
// 128KB table into LDS. Features written planar [level][point] as fp16x2
// (exact same fp32->fp16 conversion point as the fused kernel).
// ============================================================================
__global__ __launch_bounds__(1024, 4) void nerf_encode(
    const float* __restrict__ x,
    const float* __restrict__ embed,
    unsigned* __restrict__ ws, int B, NsParam ns)
{
    __shared__ f32x2 tab[TSIZE];   // 128 KB -> 1 block/CU, 16 waves resident
    const int tid = threadIdx.x;
    const int base = blockIdx.x * CHUNK;

    // Load this block's point coords once; clamp once (reused by all levels).
    float cx[8], cy[8], cz[8];
    int pidx[8];
    #pragma unroll
    for (int p = 0; p < 8; ++p) {
        int idx = base + p * 1024 + tid;
        pidx[p] = idx;
        float px = 0.0f, py = 0.0f, pz = 0.0f;
        if (idx < B) {
            const float* xp = x + (size_t)idx * 6;
            f32x2 a = *(const f32x2*)xp;   // 24B stride -> 8B aligned
            px = a.x; py = a.y; pz = xp[2];
        }
        cx[p] = fminf(fmaxf((px + 5.0f) / 10.0f, 0.0f), 0.999999f);
        cy[p] = fminf(fmaxf((py + 5.0f) / 10.0f, 0.0f), 0.999999f);
        cz[p] = fminf(fmaxf((pz + 5.0f) / 10.0f, 0.0f), 0.999999f);
    }

    for (int l = 0; l < NLEVEL; ++l) {
        __syncthreads();   // WAR: previous level's gathers done before overwrite
        // stage 128 KB table: 8192 f32x4 over 1024 threads = 8 per thread
        {
            const f32x4* src = (const f32x4*)(embed + (size_t)l * (TSIZE * 2));
            f32x4* dst = (f32x4*)tab;
            #pragma unroll
            for (int j = 0; j < 8; ++j) dst[tid + 1024 * j] = src[tid + 1024 * j];
        }
        __syncthreads();

        const int n = ns.n[l];
        const float fn = (float)n;
        const int np1 = n + 1, np1sq = np1 * np1;
        const bool dense = (ns.densemask >> l) & 1u;
        unsigned* wplane = ws + (size_t)l * B;

        #pragma unroll
        for (int p = 0; p < 8; ++p) {
            int idx = pidx[p];
            if (idx >= B) break;
            float xl0 = cx[p] * fn, xl1 = cy[p] * fn, xl2 = cz[p] * fn;
            float f0 = floorf(xl0), f1 = floorf(xl1), f2 = floorf(xl2);
            int i0 = (int)f0, i1 = (int)f1, i2 = (int)f2;
            float w0 = xl0 - f0, w1 = xl1 - f1, w2 = xl2 - f2;

            f32x2 fe[8];
            if (dense) {   // uniform branch (levels 0,1 only)
                int dx0 = i0 * np1sq, dy0 = i1 * np1;
                #pragma unroll
                for (int c = 0; c < 8; ++c) {
                    int o0 = (c >> 2) & 1, o1 = (c >> 1) & 1, o2 = c & 1;
                    int di = dx0 + (o0 ? np1sq : 0) + dy0 + (o1 ? np1 : 0) + i2 + o2;
                    fe[c] = tab[di];
                }
            } else {
                unsigned hx0 = (unsigned)i0, hx1 = hx0 + 1u;
                unsigned hy0 = (unsigned)i1 * 2654435761u, hy1 = hy0 + 2654435761u;
                unsigned hz0 = (unsigned)i2 * 805459861u,  hz1 = hz0 + 805459861u;
                #pragma unroll
                for (int c = 0; c < 8; ++c) {
                    int o0 = (c >> 2) & 1, o1 = (c >> 1) & 1, o2 = c & 1;
                    unsigned h = (o0 ? hx1 : hx0) ^ (o1 ? hy1 : hy0) ^ (o2 ? hz1 : hz0);
                    fe[c] = tab[h & (TSIZE - 1)];
                }
            }

            float u0 = 1.0f - w0, u1 = 1.0f - w1, u2 = 1.0f - w2;
            float wxy[4] = { u0 * u1, u0 * w1, w0 * u1, w0 * w1 };
            float a0 = 0.0f, a1 = 0.0f;
            #pragma unroll
            for (int c = 0; c < 8; ++c) {
                float ww = wxy[c >> 1] * ((c & 1) ? w2 : u2);
                a0 = fmaf(fe[c].x, ww, a0);
                a1 = fmaf(fe[c].y, ww, a1);
            }
            union { _Float16 h2[2]; unsigned u; } pk;
            pk.h2[0] = (_Float16)a0; pk.h2[1] = (_Float16)a1;
            __builtin_nontemporal_store(pk.u, wplane + idx);
        }
    }
}

// ============================================================================
// Phase B: MFMA MLP, features read from workspace.
// Planar fp16x2 [level][point] drops straight into the B-fragments:
// lane (pt,q) k=4q+j -> levels {2q,2q+1} (bf0) and {8+2q,9+2q} (bf1),
// one coalesced u32 load each. 16 line-requests/tile vs 2048 fused.
// ============================================================================
__global__ __launch_bounds__(256) void nerf_mlp(
    const float* __restrict__ x,
    const unsigned* __restrict__ ws,
    const float* __restrict__ dW0, const float* __restrict__ db0,
    const float* __restrict__ dW1, const float* __restrict__ db1,
    const float* __restrict__ cW0, const float* __restrict__ cb0,
    const float* __restrict__ cW1, const float* __restrict__ cb1,
    const float* __restrict__ cW2, const float* __restrict__ cb2,
    float* __restrict__ out, int B)
{
    const int lane = threadIdx.x & 63;
    const int pt = lane & 15;
    const int q  = lane >> 4;
    const int wavesPerBlock = blockDim.x >> 6;
    const int waveId = blockIdx.x * wavesPerBlock + (threadIdx.x >> 6);
    const int waveStride = gridDim.x * wavesPerBlock;
    const int numTiles = B >> 4;

    // resident weight A-fragments (80 VGPRs, loaded once)
    Frag wdW0[4][2], wdW1[4], wcW0[4][2], wcW1[4][4], wcW2[4];
    #pragma unroll
    for (int t = 0; t < 4; ++t)
        #pragma unroll
        for (int c = 0; c < 2; ++c)
            wdW0[t][c] = load_wfrag(dW0, 64, 16 * c, q, 16 * t + pt, 32, 64);
    #pragma unroll
    for (int c = 0; c < 4; ++c)
        wdW1[c] = load_wfrag(dW1, 16, 16 * c, q, pt, 64, 16);
    #pragma unroll
    for (int t = 0; t < 4; ++t)
        #pragma unroll
        for (int c = 0; c < 2; ++c)
            wcW0[t][c] = load_wfrag(cW0, 64, 16 * c, q, 16 * t + pt, 19, 64);
    #pragma unroll
    for (int t = 0; t < 4; ++t)
        #pragma unroll
        for (int c = 0; c < 4; ++c)
            wcW1[t][c] = load_wfrag(cW1, 64, 16 * c, q, 16 * t + pt, 64, 64);
    #pragma unroll
    for (int c = 0; c < 4; ++c)
        wcW2[c] = load_wfrag(cW2, 3, 16 * c, q, pt, 64, 3);

    const unsigned* p0 = ws + (size_t)(2 * q) * B;
    const unsigned* p1 = ws + (size_t)(2 * q + 1) * B;
    const unsigned* p2 = ws + (size_t)(8 + 2 * q) * B;
    const unsigned* p3 = ws + (size_t)(9 + 2 * q) * B;

    for (int tile = waveId; tile < numTiles; tile += waveStride) {
        const int ptg = tile * 16 + pt;
        // features (coalesced: 16 consecutive points per q-group per plane)
        Frag bf0, bf1;
        bf0.i[0] = (int)__builtin_nontemporal_load(p0 + ptg);
        bf0.i[1] = (int)__builtin_nontemporal_load(p1 + ptg);
        bf1.i[0] = (int)__builtin_nontemporal_load(p2 + ptg);
        bf1.i[1] = (int)__builtin_nontemporal_load(p3 + ptg);

        // view dir for this lane's own point
        const float* xp = x + (size_t)ptg * 6;
        f32x2 x23 = *(const f32x2*)(xp + 2);
        f32x2 x45 = *(const f32x2*)(xp + 4);
        float vx = x23.y, vy = x45.x, vz = x45.y;

        // per-iteration opaque bias pointers (defeats LICM register hoisting)
        const float* db0o = db0; const float* db1o = db1;
        const float* cb0o = cb0; const float* cb1o = cb1;
        const float* cb2o = cb2;
        opaque(db0o); opaque(db1o); opaque(cb0o); opaque(cb1o); opaque(cb2o);

        // L0: h64 = dW0^T @ feats (4 out-tiles, K=32)
        f32x4 acc[4];
        #pragma unroll
        for (int t = 0; t < 4; ++t) {
            acc[t] = *(const f32x4*)(db0o + 16 * t + 4 * q);
            acc[t] = mfma16(wdW0[t][0], bf0, acc[t]);
            acc[t] = mfma16(wdW0[t][1], bf1, acc[t]);
        }
        Frag bh[4];
        #pragma unroll
        for (int c = 0; c < 4; ++c) bh[c] = actpack(acc[c]);

        // L1: h16 = dW1^T @ relu(h64) (1 tile, K=64)
        f32x4 h = *(const f32x4*)(db1o + 4 * q);
        #pragma unroll
        for (int c = 0; c < 4; ++c) h = mfma16(wdW1[c], bh[c], h);

        float dens = sigmoidf(h[0]);            // row 0 lives at q==0, reg 0
        Frag bcin0, bcin1;
        {
            float a0v = (q == 0) ? dens : fmaxf(h[0], 0.0f);
            bcin0.v[0] = (_Float16)a0v;
            bcin0.v[1] = (_Float16)fmaxf(h[1], 0.0f);
            bcin0.v[2] = (_Float16)fmaxf(h[2], 0.0f);
            bcin0.v[3] = (_Float16)fmaxf(h[3], 0.0f);
            // k=16+4q+j: q==0 holds k16..19 = (vx,vy,vz,0) of its own point
            bcin1.v[0] = (_Float16)((q == 0) ? vx : 0.0f);
            bcin1.v[1] = (_Float16)((q == 0) ? vy : 0.0f);
            bcin1.v[2] = (_Float16)((q == 0) ? vz : 0.0f);
            bcin1.v[3] = (_Float16)0.0f;
        }

        // L2: c1 = cW0^T @ cin (4 out-tiles, K=19 padded to 32)
        #pragma unroll
        for (int t = 0; t < 4; ++t) {
            acc[t] = *(const f32x4*)(cb0o + 16 * t + 4 * q);
            acc[t] = mfma16(wcW0[t][0], bcin0, acc[t]);
            acc[t] = mfma16(wcW0[t][1], bcin1, acc[t]);
        }
        Frag bc[4];
        #pragma unroll
        for (int c = 0; c < 4; ++c) bc[c] = actpack(acc[c]);

        // L3: c2 = cW1^T @ relu(c1) (4 out-tiles, K=64)
        #pragma unroll
        for (int t = 0; t < 4; ++t) {
            acc[t] = *(const f32x4*)(cb1o + 16 * t + 4 * q);
            #pragma unroll
            for (int c = 0; c < 4; ++c) acc[t] = mfma16(wcW1[t][c], bc[c], acc[t]);
        }
        Frag bd[4];
        #pragma unroll
        for (int c = 0; c < 4; ++c) bd[c] = actpack(acc[c]);

        // L4: col = cW2^T @ relu(c2) (rows 0..2, K=64)
        float b0 = cb2o[0], b1 = cb2o[1], b2 = cb2o[2];
        f32x4 fo;
        fo[0] = (q == 0) ? b0 : 0.0f;
        fo[1] = (q == 0) ? b1 : 0.0f;
        fo[2] = (q == 0) ? b2 : 0.0f;
        fo[3] = 0.0f;
        #pragma unroll
        for (int c = 0; c < 4; ++c) fo = mfma16(wcW2[c], bd[c], fo);

        if (q == 0) {
            f32x4 o;
            o[0] = dens;
            o[1] = sigmoidf(fo[0]);
            o[2] = sigmoidf(fo[1]);
            o[3] = sigmoidf(fo[2]);
            *(f32x4*)(out + (size_t)ptg * 4) = o;
        }
    }
}

// ============================================================================
// Fallback: fused single kernel (round-1 version) if ws_size is insufficient.
// ============================================================================
__device__ __forceinline__ void enc_issue(
    float px, float py, float pz,
    const float fn_[4], const float* const eb_[4],
    const int np1_[4], const int np1sq_[4], const bool dense_[4],
    f32x2 fe[4][8], float w_[4][3])
{
    float cx = fminf(fmaxf((px + 5.0f) / 10.0f, 0.0f), 0.999999f);
    float cy = fminf(fmaxf((py + 5.0f) / 10.0f, 0.0f), 0.999999f);
    float cz = fminf(fmaxf((pz + 5.0f) / 10.0f, 0.0f), 0.999999f);

    #pragma unroll
    for (int d = 0; d < 4; ++d) {
        float fn = fn_[d];
        float xl0 = cx * fn, xl1 = cy * fn, xl2 = cz * fn;
        float f0 = floorf(xl0), f1 = floorf(xl1), f2 = floorf(xl2);
        int i0 = (int)f0, i1 = (int)f1, i2 = (int)f2;
        w_[d][0] = xl0 - f0; w_[d][1] = xl1 - f1; w_[d][2] = xl2 - f2;

        unsigned hx0 = (unsigned)i0, hx1 = hx0 + 1u;
        unsigned hy0 = (unsigned)i1 * 2654435761u, hy1 = hy0 + 2654435761u;
        unsigned hz0 = (unsigned)i2 * 805459861u,  hz1 = hz0 + 805459861u;
        int dx0 = 0, dx1 = 0, dy0 = 0, dy1 = 0;
        if (d < 2) {
            dx0 = i0 * np1sq_[d]; dx1 = dx0 + np1sq_[d];
            dy0 = i1 * np1_[d];   dy1 = dy0 + np1_[d];
        }
        #pragma unroll
        for (int c = 0; c < 8; ++c) {
            int o0 = (c >> 2) & 1, o1 = (c >> 1) & 1, o2 = c & 1;
            unsigned h = (o0 ? hx1 : hx0) ^ (o1 ? hy1 : hy0) ^ (o2 ? hz1 : hz0);
            int ind = (int)(h & (TSIZE - 1));
            if (d < 2) {
                int di = (o0 ? dx1 : dx0) + (o1 ? dy1 : dy0) + i2 + o2;
                ind = dense_[d] ? di : ind;
            }
            fe[d][c] = *(const f32x2*)(eb_[d] + (size_t)ind * 2);
        }
    }
}

__global__ __launch_bounds__(256) void nerf_fused(
    const float* __restrict__ x,
    const float* __restrict__ embed,
    const float* __restrict__ dW0, const float* __restrict__ db0,
    const float* __restrict__ dW1, const float* __restrict__ db1,
    const float* __restrict__ cW0, const float* __restrict__ cb0,
    const float* __restrict__ cW1, const float* __restrict__ cb1,
    const float* __restrict__ cW2, const float* __restrict__ cb2,
    float* __restrict__ out, int B, NsParam ns)
{
    const int lane = threadIdx.x & 63;
    const int pt = lane & 15;
    const int q  = lane >> 4;
    const int wavesPerBlock = blockDim.x >> 6;
    const int waveId = blockIdx.x * wavesPerBlock + (threadIdx.x >> 6);
    const int waveStride = gridDim.x * wavesPerBlock;
    const int numTiles = B >> 4;

    Frag wdW0[4][2], wdW1[4], wcW0[4][2], wcW1[4][4], wcW2[4];
    #pragma unroll
    for (int t = 0; t < 4; ++t)
        #pragma unroll
        for (int c = 0; c < 2; ++c)
            wdW0[t][c] = load_wfrag(dW0, 64, 16 * c, q, 16 * t + pt, 32, 64);
    #pragma unroll
    for (int c = 0; c < 4; ++c)
        wdW1[c] = load_wfrag(dW1, 16, 16 * c, q, pt, 64, 16);
    #pragma unroll
    for (int t = 0; t < 4; ++t)
        #pragma unroll
        for (int c = 0; c < 2; ++c)
            wcW0[t][c] = load_wfrag(cW0, 64, 16 * c, q, 16 * t + pt, 19, 64);
    #pragma unroll
    for (int t = 0; t < 4; ++t)
        #pragma unroll
        for (int c = 0; c < 4; ++c)
            wcW1[t][c] = load_wfrag(cW1, 64, 16 * c, q, 16 * t + pt, 64, 64);
    #pragma unroll
    for (int c = 0; c < 4; ++c)
        wcW2[c] = load_wfrag(cW2, 3, 16 * c, q, pt, 64, 3);

    float fn_[4];
    const float* eb_[4];
    int np1_[4], np1sq_[4];
    bool dense_[4];
    #pragma unroll
    for (int d = 0; d < 4; ++d) {
        int base = (d < 2) ? (d) : (8 + (d - 2));
        int lvl = base + 2 * q;
        int n = qsel(q, ns.n[base], ns.n[base + 2], ns.n[base + 4], ns.n[base + 6]);
        fn_[d] = (float)n;
        np1_[d] = n + 1;
        np1sq_[d] = (n + 1) * (n + 1);
        dense_[d] = (ns.densemask >> lvl) & 1u;
        eb_[d] = embed + (size_t)lvl * (TSIZE * 2);
    }

    for (int tile = waveId; tile < numTiles; tile += waveStride) {
        const int ptg = tile * 16 + pt;
        const float* xp = x + (size_t)ptg * 6;
        f32x2 x01 = *(const f32x2*)(xp);
        f32x2 x23 = *(const f32x2*)(xp + 2);
        f32x2 x45 = *(const f32x2*)(xp + 4);
        float vx = x23.y, vy = x45.x, vz = x45.y;

        f32x2 fe[4][8];
        float w_[4][3];
        enc_issue(x01.x, x01.y, x23.x, fn_, eb_, np1_, np1sq_, dense_, fe, w_);

        Frag bf0, bf1;
        #pragma unroll
        for (int d = 0; d < 4; ++d) {
            float w0 = w_[d][0], w1 = w_[d][1], w2 = w_[d][2];
            float u0 = 1.0f - w0, u1 = 1.0f - w1, u2 = 1.0f - w2;
            float wxy[4] = { u0 * u1, u0 * w1, w0 * u1, w0 * w1 };
            float a0 = 0.0f, a1 = 0.0f;
            #pragma unroll
            for (int c = 0; c < 8; ++c) {
                float ww = wxy[c >> 1] * ((c & 1) ? w2 : u2);
                a0 = fmaf(fe[d][c].x, ww, a0);
                a1 = fmaf(fe[d][c].y, ww, a1);
            }
            if (d == 0)      { bf0.v[0] = (_Float16)a0; bf0.v[1] = (_Float16)a1; }
            else if (d == 1) { bf0.v[2] = (_Float16)a0; bf0.v[3] = (_Float16)a1; }
            else if (d == 2) { bf1.v[0] = (_Float16)a0; bf1.v[1] = (_Float16)a1; }
            else             { bf1.v[2] = (_Float16)a0; bf1.v[3] = (_Float16)a1; }
        }

        const float* db0o = db0; const float* db1o = db1;
        const float* cb0o = cb0; const float* cb1o = cb1;
        const float* cb2o = cb2;
        opaque(db0o); opaque(db1o); opaque(cb0o); opaque(cb1o); opaque(cb2o);

        f32x4 acc[4];
        #pragma unroll
        for (int t = 0; t < 4; ++t) {
            acc[t] = *(const f32x4*)(db0o + 16 * t + 4 * q);
            acc[t] = mfma16(wdW0[t][0], bf0, acc[t]);
            acc[t] = mfma16(wdW0[t][1], bf1, acc[t]);
        }
        Frag bh[4];
        #pragma unroll
        for (int c = 0; c < 4; ++c) bh[c] = actpack(acc[c]);

        f32x4 h = *(const f32x4*)(db1o + 4 * q);
        #pragma unroll
        for (int c = 0; c < 4; ++c) h = mfma16(wdW1[c], bh[c], h);

        float dens = sigmoidf(h[0]);
        Frag bcin0, bcin1;
        {
            float a0v = (q == 0) ? dens : fmaxf(h[0], 0.0f);
            bcin0.v[0] = (_Float16)a0v;
            bcin0.v[1] = (_Float16)fmaxf(h[1], 0.0f);
            bcin0.v[2] = (_Float16)fmaxf(h[2], 0.0f);
            bcin0.v[3] = (_Float16)fmaxf(h[3], 0.0f);
            bcin1.v[0] = (_Float16)((q == 0) ? vx : 0.0f);
            bcin1.v[1] = (_Float16)((q == 0) ? vy : 0.0f);
            bcin1.v[2] = (_Float16)((q == 0) ? vz : 0.0f);
            bcin1.v[3] = (_Float16)0.0f;
        }

        #pragma unroll
        for (int t = 0; t < 4; ++t) {
            acc[t] = *(const f32x4*)(cb0o + 16 * t + 4 * q);
            acc[t] = mfma16(wcW0[t][0], bcin0, acc[t]);
            acc[t] = mfma16(wcW0[t][1], bcin1, acc[t]);
        }
        Frag bc[4];
        #pragma unroll
        for (int c = 0; c < 4; ++c) bc[c] = actpack(acc[c]);

        #pragma unroll
        for (int t = 0; t < 4; ++t) {
            acc[t] = *(const f32x4*)(cb1o + 16 * t + 4 * q);
            #pragma unroll
            for (int c = 0; c < 4; ++c) acc[t] = mfma16(wcW1[t][c], bc[c], acc[t]);
        }
        Frag bd[4];
        #pragma unroll
        for (int c = 0; c < 4; ++c) bd[c] = actpack(acc[c]);

        float b0 = cb2o[0], b1 = cb2o[1], b2 = cb2o[2];
        f32x4 fo;
        fo[0] = (q == 0) ? b0 : 0.0f;
        fo[1] = (q == 0) ? b1 : 0.0f;
        fo[2] = (q == 0) ? b2 : 0.0f;
        fo[3] = 0.0f;
        #pragma unroll
        for (int c = 0; c < 4; ++c) fo = mfma16(wcW2[c], bd[c], fo);

        if (q == 0) {
            f32x4 o;
            o[0] = dens;
            o[1] = sigmoidf(fo[0]);
            o[2] = sigmoidf(fo[1]);
            o[3] = sigmoidf(fo[2]);
            *(f32x4*)(out + (size_t)ptg * 4) = o;
        }
    }
}

extern "C" void kernel_launch(void* const* d_in, const int* in_sizes, int n_in,
                              void* d_out, int out_size, void* d_ws, size_t ws_size,
                              hipStream_t stream) {
    const float* x    = (const float*)d_in[0];
    const float* embed= (const float*)d_in[1];
    const float* dW0  = (const float*)d_in[2];
    const float* db0  = (const float*)d_in[3];
    const float* dW1  = (const float*)d_in[4];
    const float* db1  = (const float*)d_in[5];
    const float* cW0  = (const float*)d_in[6];
    const float* cb0  = (const float*)d_in[7];
    const float* cW1  = (const float*)d_in[8];
    const float* cb1  = (const float*)d_in[9];
    const float* cW2  = (const float*)d_in[10];
    const float* cb2  = (const float*)d_in[11];
    float* out = (float*)d_out;

    int B = in_sizes[0] / 6;

    // Replicate numpy's NS computation bit-for-bit (same libm on this host).
    NsParam ns;
    double g = exp((log(512.0) - log(16.0)) / 15.0);
    ns.densemask = 0;
    for (int i = 0; i < NLEVEL; ++i) {
        ns.n[i] = (int)(16.0 * pow(g, (double)i));
        long long np1 = ns.n[i] + 1;
        if (np1 * np1 * np1 <= TSIZE) ns.densemask |= (1u << i);
    }

    size_t wsNeed = (size_t)NLEVEL * (size_t)B * 4;   // fp16x2 per (level,point)
    if (ws_size >= wsNeed && d_ws != nullptr) {
        unsigned* ws = (unsigned*)d_ws;
        int gridA = (B + CHUNK - 1) / CHUNK;          // 256 at B=2M: 1 block/CU
        nerf_encode<<<gridA, 1024, 0, stream>>>(x, embed, ws, B, ns);
        nerf_mlp<<<2048, 256, 0, stream>>>(x, ws,
            dW0, db0, dW1, db1, cW0, cb0, cW1, cb1, cW2, cb2, out, B);
    } else {
        nerf_fused<<<2048, 256, 0, stream>>>(x, embed,
            dW0, db0, dW1, db1, cW0, cb0, cW1, cb1, cW2, cb2, out, B, ns);
    }
}

// Round 3
// 366.811 us; speedup vs baseline: 2.8990x; 1.0324x over previous
//
#include <hip/hip_runtime.h>
#include <math.h>

#define NLEVEL 16
#define TSIZE 16384
#define CHUNK 8192   // points per encode block

using half4 = __attribute__((ext_vector_type(4))) _Float16;
using f32x4 = __attribute__((ext_vector_type(4))) float;
using f32x2 = __attribute__((ext_vector_type(2))) float;
using u32x2 = __attribute__((ext_vector_type(2))) unsigned;

struct NsParam { int n[NLEVEL]; unsigned densemask; };

union Frag { half4 v; int i[2]; };

// Block loop-invariant code motion from hoisting per-tile bias loads into
// permanently-live VGPRs: make the pointer "new" every iteration.
__device__ __forceinline__ void opaque(const float*& p) {
    asm("" : "+v"(p));
}

// A-fragment for mfma_f32_16x16x16f16 of W^T (W row-major [K][N] fp32):
// lane (pt=lane&15, q=lane>>4) holds A[m=out][k=k0+4q+j], j=0..3.
__device__ __forceinline__ Frag load_wfrag(const float* __restrict__ W, int ldn,
                                           int k0, int q, int out,
                                           int kmax, int omax) {
    Frag f;
    #pragma unroll
    for (int j = 0; j < 4; ++j) {
        int k = k0 + 4 * q + j;
        float v = (k < kmax && out < omax) ? W[k * ldn + out] : 0.0f;
        f.v[j] = (_Float16)v;
    }
    return f;
}

__device__ __forceinline__ f32x4 mfma16(const Frag& a, const Frag& b, f32x4 c) {
    return __builtin_amdgcn_mfma_f32_16x16x16f16(a.v, b.v, c, 0, 0, 0);
}

// relu + cvt: C-tile f32x4 -> B-fragment half4 (layouts match for K=16!)
__device__ __forceinline__ Frag actpack(f32x4 a) {
    Frag f;
    #pragma unroll
    for (int j = 0; j < 4; ++j) f.v[j] = (_Float16)fmaxf(a[j], 0.0f);
    return f;
}

__device__ __forceinline__ float sigmoidf(float x) {
    return 1.0f / (1.0f + expf(-x));
}

// q-select among 4 values (q = lane>>4)
__device__ __forceinline__ int qsel(int q, int a, int b, int c, int d) {
    return (q & 2) ? ((q & 1) ? d : c) : ((q & 1) ? b : a);
}

// Compute one point's 8 table indices and ISSUE the 8 LDS gathers.
// Interpolation weights returned for later consumption (1-point lookahead).
__device__ __forceinline__ void gather_issue(
    const f32x2* __restrict__ tab,
    float cxp, float cyp, float czp,
    float fn, int np1, int np1sq, int dense,
    f32x2 fe[8], float& w0, float& w1, float& w2)
{
    float xl0 = cxp * fn, xl1 = cyp * fn, xl2 = czp * fn;
    float f0 = floorf(xl0), f1 = floorf(xl1), f2 = floorf(xl2);
    int i0 = (int)f0, i1 = (int)f1, i2 = (int)f2;
    w0 = xl0 - f0; w1 = xl1 - f1; w2 = xl2 - f2;
    if (dense) {   // wave-uniform branch (levels 0,1 only)
        int d000 = i0 * np1sq + i1 * np1 + i2;
        #pragma unroll
        for (int c = 0; c < 8; ++c) {
            int o0 = (c >> 2) & 1, o1 = (c >> 1) & 1, o2 = c & 1;
            fe[c] = tab[d000 + (o0 ? np1sq : 0) + (o1 ? np1 : 0) + o2];
        }
    } else {
        unsigned hx0 = (unsigned)i0, hx1 = hx0 + 1u;
        unsigned hy0 = (unsigned)i1 * 2654435761u, hy1 = hy0 + 2654435761u;
        unsigned hz0 = (unsigned)i2 * 805459861u,  hz1 = hz0 + 805459861u;
        #pragma unroll
        for (int c = 0; c < 8; ++c) {
            int o0 = (c >> 2) & 1, o1 = (c >> 1) & 1, o2 = c & 1;
            unsigned h = (o0 ? hx1 : hx0) ^ (o1 ? hy1 : hy0) ^ (o2 ? hz1 : hz0);
            fe[c] = tab[h & (TSIZE - 1)];
        }
    }
}

// ============================================================================
// Phase A: hash-grid encode, level table staged in LDS (L2-gather-rate fix,
// round 2). Round-3 deltas: (1) 1-point gather LOOKAHEAD so each point's
// interpolation VALU hides the next point's LDS latency; (2) outputs written
// as level-PAIR u32x2 planes so phase B needs 2 loads instead of 4.
// ============================================================================
__global__ __launch_bounds__(1024, 4) void nerf_encode(
    const float* __restrict__ x,
    const float* __restrict__ embed,
    unsigned* __restrict__ ws, int B, NsParam ns)
{
    __shared__ f32x2 tab[TSIZE];   // 128 KB -> 1 block/CU, 16 waves resident
    const int tid = threadIdx.x;
    const int base = blockIdx.x * CHUNK;

    // Load this block's point coords once; clamp once (reused by all levels).
    float cx[8], cy[8], cz[8];
    #pragma unroll
    for (int p = 0; p < 8; ++p) {
        int idx = base + p * 1024 + tid;
        float px = 0.0f, py = 0.0f, pz = 0.0f;
        if (idx < B) {
            const float* xp = x + (size_t)idx * 6;
            f32x2 a = *(const f32x2*)xp;   // 24B stride -> 8B aligned
            px = a.x; py = a.y; pz = xp[2];
        }
        cx[p] = fminf(fmaxf((px + 5.0f) / 10.0f, 0.0f), 0.999999f);
        cy[p] = fminf(fmaxf((py + 5.0f) / 10.0f, 0.0f), 0.999999f);
        cz[p] = fminf(fmaxf((pz + 5.0f) / 10.0f, 0.0f), 0.999999f);
    }

    unsigned stash[8];   // even-level fp16x2 results, paired on odd levels

    for (int l = 0; l < NLEVEL; ++l) {
        __syncthreads();   // WAR: previous level's gathers done before overwrite
        // stage 128 KB table: 8192 f32x4 over 1024 threads = 8 per thread
        {
            const f32x4* src = (const f32x4*)(embed + (size_t)l * (TSIZE * 2));
            f32x4* dst = (f32x4*)tab;
            #pragma unroll
            for (int j = 0; j < 8; ++j) dst[tid + 1024 * j] = src[tid + 1024 * j];
        }
        __syncthreads();

        const int n = ns.n[l];
        const float fn = (float)n;
        const int np1 = n + 1, np1sq = np1 * np1;
        const int dense = (ns.densemask >> l) & 1;

        // 1-ahead software pipeline: two static buffers, fully unrolled.
        f32x2 fe[2][8];
        float w0s[2], w1s[2], w2s[2];
        gather_issue(tab, cx[0], cy[0], cz[0], fn, np1, np1sq, dense,
                     fe[0], w0s[0], w1s[0], w2s[0]);

        #pragma unroll
        for (int p = 0; p < 8; ++p) {
            if (p + 1 < 8)
                gather_issue(tab, cx[p + 1], cy[p + 1], cz[p + 1],
                             fn, np1, np1sq, dense,
                             fe[(p + 1) & 1], w0s[(p + 1) & 1],
                             w1s[(p + 1) & 1], w2s[(p + 1) & 1]);

            float w0 = w0s[p & 1], w1 = w1s[p & 1], w2 = w2s[p & 1];
            float u0 = 1.0f - w0, u1 = 1.0f - w1, u2 = 1.0f - w2;
            float wxy[4] = { u0 * u1, u0 * w1, w0 * u1, w0 * w1 };
            float a0 = 0.0f, a1 = 0.0f;
            #pragma unroll
            for (int c = 0; c < 8; ++c) {
                float ww = wxy[c >> 1] * ((c & 1) ? w2 : u2);
                a0 = fmaf(fe[p & 1][c].x, ww, a0);
                a1 = fmaf(fe[p & 1][c].y, ww, a1);
            }
            union { _Float16 h2[2]; unsigned u; } pk;
            pk.h2[0] = (_Float16)a0; pk.h2[1] = (_Float16)a1;
            if ((l & 1) == 0) {
                stash[p] = pk.u;
            } else {
                int idx = base + p * 1024 + tid;
                if (idx < B) {
                    u32x2 st; st.x = stash[p]; st.y = pk.u;
                    *((u32x2*)ws + (size_t)(l >> 1) * B + idx) = st;  // cacheable
                }
            }
        }
    }
}

// ============================================================================
// Phase B: MFMA MLP. Round-3 deltas: (1) features as u32x2 pair-planes
// (2 loads/tile instead of 4); (2) cross-tile prefetch (T14) -- tile t+1's
// feature/view loads issued before tile t's MFMA chain, hiding ~900cy
// L3/HBM latency under the MLP.
// Pair plane k holds levels {2k,2k+1}; lane (pt,q): bf0 <- plane q,
// bf1 <- plane 4+q (levels {2q,2q+1} and {8+2q,9+2q}).
// ============================================================================
__global__ __launch_bounds__(256) void nerf_mlp(
    const float* __restrict__ x,
    const unsigned* __restrict__ ws,
    const float* __restrict__ dW0, const float* __restrict__ db0,
    const float* __restrict__ dW1, const float* __restrict__ db1,
    const float* __restrict__ cW0, const float* __restrict__ cb0,
    const float* __restrict__ cW1, const float* __restrict__ cb1,
    const float* __restrict__ cW2, const float* __restrict__ cb2,
    float* __restrict__ out, int B)
{
    const int lane = threadIdx.x & 63;
    const int pt = lane & 15;
    const int q  = lane >> 4;
    const int wavesPerBlock = blockDim.x >> 6;
    const int waveId = blockIdx.x * wavesPerBlock + (threadIdx.x >> 6);
    const int waveStride = gridDim.x * wavesPerBlock;
    const int numTiles = B >> 4;

    // resident weight A-fragments (80 VGPRs, loaded once)
    Frag wdW0[4][2], wdW1[4], wcW0[4][2], wcW1[4][4], wcW2[4];
    #pragma unroll
    for (int t = 0; t < 4; ++t)
        #pragma unroll
        for (int c = 0; c < 2; ++c)
            wdW0[t][c] = load_wfrag(dW0, 64, 16 * c, q, 16 * t + pt, 32, 64);
    #pragma unroll
    for (int c = 0; c < 4; ++c)
        wdW1[c] = load_wfrag(dW1, 16, 16 * c, q, pt, 64, 16);
    #pragma unroll
    for (int t = 0; t < 4; ++t)
        #pragma unroll
        for (int c = 0; c < 2; ++c)
            wcW0[t][c] = load_wfrag(cW0, 64, 16 * c, q, 16 * t + pt, 19, 64);
    #pragma unroll
    for (int t = 0; t < 4; ++t)
        #pragma unroll
        for (int c = 0; c < 4; ++c)
            wcW1[t][c] = load_wfrag(cW1, 64, 16 * c, q, 16 * t + pt, 64, 64);
    #pragma unroll
    for (int c = 0; c < 4; ++c)
        wcW2[c] = load_wfrag(cW2, 3, 16 * c, q, pt, 64, 3);

    const u32x2* wpl0 = (const u32x2*)ws + (size_t)q * B;
    const u32x2* wpl1 = (const u32x2*)ws + (size_t)(4 + q) * B;

    int tile = waveId;
    if (tile >= numTiles) return;

    // prologue: prefetch first tile's features + view dir
    Frag nf0, nf1;
    float nvx, nvy, nvz;
    {
        int ptg = tile * 16 + pt;
        u32x2 a = __builtin_nontemporal_load(wpl0 + ptg);
        u32x2 b = __builtin_nontemporal_load(wpl1 + ptg);
        nf0.i[0] = (int)a.x; nf0.i[1] = (int)a.y;
        nf1.i[0] = (int)b.x; nf1.i[1] = (int)b.y;
        const float* xp = x + (size_t)ptg * 6;
        nvx = xp[3];
        f32x2 v45 = *(const f32x2*)(xp + 4);
        nvy = v45.x; nvz = v45.y;
    }

    for (;;) {
        const int ptg = tile * 16 + pt;
        int next = tile + waveStride;
        bool hasNext = next < numTiles;

        Frag bf0 = nf0, bf1 = nf1;
        float vx = nvx, vy = nvy, vz = nvz;

        // issue NEXT tile's loads now; they complete under this tile's MLP
        if (hasNext) {
            int ptg2 = next * 16 + pt;
            u32x2 a = __builtin_nontemporal_load(wpl0 + ptg2);
            u32x2 b = __builtin_nontemporal_load(wpl1 + ptg2);
            nf0.i[0] = (int)a.x; nf0.i[1] = (int)a.y;
            nf1.i[0] = (int)b.x; nf1.i[1] = (int)b.y;
            const float* xp = x + (size_t)ptg2 * 6;
            nvx = xp[3];
            f32x2 v45 = *(const f32x2*)(xp + 4);
            nvy = v45.x; nvz = v45.y;
        }

        // per-iteration opaque bias pointers (defeats LICM register hoisting;
        // bias lines stay L1-hot so the reloads are cheap)
        const float* db0o = db0; const float* db1o = db1;
        const float* cb0o = cb0; const float* cb1o = cb1;
        const float* cb2o = cb2;
        opaque(db0o); opaque(db1o); opaque(cb0o); opaque(cb1o); opaque(cb2o);

        // L0: h64 = dW0^T @ feats (4 out-tiles, K=32)
        f32x4 acc[4];
        #pragma unroll
        for (int t = 0; t < 4; ++t) {
            acc[t] = *(const f32x4*)(db0o + 16 * t + 4 * q);
            acc[t] = mfma16(wdW0[t][0], bf0, acc[t]);
            acc[t] = mfma16(wdW0[t][1], bf1, acc[t]);
        }
        Frag bh[4];
        #pragma unroll
        for (int c = 0; c < 4; ++c) bh[c] = actpack(acc[c]);

        // L1: h16 = dW1^T @ relu(h64) (1 tile, K=64)
        f32x4 h = *(const f32x4*)(db1o + 4 * q);
        #pragma unroll
        for (int c = 0; c < 4; ++c) h = mfma16(wdW1[c], bh[c], h);

        float dens = sigmoidf(h[0]);            // row 0 lives at q==0, reg 0
        Frag bcin0, bcin1;
        {
            float a0v = (q == 0) ? dens : fmaxf(h[0], 0.0f);
            bcin0.v[0] = (_Float16)a0v;
            bcin0.v[1] = (_Float16)fmaxf(h[1], 0.0f);
            bcin0.v[2] = (_Float16)fmaxf(h[2], 0.0f);
            bcin0.v[3] = (_Float16)fmaxf(h[3], 0.0f);
            // k=16+4q+j: q==0 holds k16..19 = (vx,vy,vz,0) of its own point
            bcin1.v[0] = (_Float16)((q == 0) ? vx : 0.0f);
            bcin1.v[1] = (_Float16)((q == 0) ? vy : 0.0f);
            bcin1.v[2] = (_Float16)((q == 0) ? vz : 0.0f);
            bcin1.v[3] = (_Float16)0.0f;
        }

        // L2: c1 = cW0^T @ cin (4 out-tiles, K=19 padded to 32)
        #pragma unroll
        for (int t = 0; t < 4; ++t) {
            acc[t] = *(const f32x4*)(cb0o + 16 * t + 4 * q);
            acc[t] = mfma16(wcW0[t][0], bcin0, acc[t]);
            acc[t] = mfma16(wcW0[t][1], bcin1, acc[t]);
        }
        Frag bc[4];
        #pragma unroll
        for (int c = 0; c < 4; ++c) bc[c] = actpack(acc[c]);

        // L3: c2 = cW1^T @ relu(c1) (4 out-tiles, K=64)
        #pragma unroll
        for (int t = 0; t < 4; ++t) {
            acc[t] = *(const f32x4*)(cb1o + 16 * t + 4 * q);
            #pragma unroll
            for (int c = 0; c < 4; ++c) acc[t] = mfma16(wcW1[t][c], bc[c], acc[t]);
        }
        Frag bd[4];
        #pragma unroll
        for (int c = 0; c < 4; ++c) bd[c] = actpack(acc[c]);

        // L4: col = cW2^T @ relu(c2) (rows 0..2, K=64)
        float b0 = cb2o[0], b1 = cb2o[1], b2 = cb2o[2];
        f32x4 fo;
        fo[0] = (q == 0) ? b0 : 0.0f;
        fo[1] = (q == 0) ? b1 : 0.0f;
        fo[2] = (q == 0) ? b2 : 0.0f;
        fo[3] = 0.0f;
        #pragma unroll
        for (int c = 0; c < 4; ++c) fo = mfma16(wcW2[c], bd[c], fo);

        if (q == 0) {
            f32x4 o;
            o[0] = dens;
            o[1] = sigmoidf(fo[0]);
            o[2] = sigmoidf(fo[1]);
            o[3] = sigmoidf(fo[2]);
            __builtin_nontemporal_store(o, (f32x4*)(out + (size_t)ptg * 4));
        }

        if (!hasNext) break;
        tile = next;
    }
}

// ============================================================================
// Fallback: fused single kernel if ws_size is insufficient (unchanged).
// ============================================================================
__device__ __forceinline__ void enc_issue(
    float px, float py, float pz,
    const float fn_[4], const float* const eb_[4],
    const int np1_[4], const int np1sq_[4], const bool dense_[4],
    f32x2 fe[4][8], float w_[4][3])
{
    float cx = fminf(fmaxf((px + 5.0f) / 10.0f, 0.0f), 0.999999f);
    float cy = fminf(fmaxf((py + 5.0f) / 10.0f, 0.0f), 0.999999f);
    float cz = fminf(fmaxf((pz + 5.0f) / 10.0f, 0.0f), 0.999999f);

    #pragma unroll
    for (int d = 0; d < 4; ++d) {
        float fn = fn_[d];
        float xl0 = cx * fn, xl1 = cy * fn, xl2 = cz * fn;
        float f0 = floorf(xl0), f1 = floorf(xl1), f2 = floorf(xl2);
        int i0 = (int)f0, i1 = (int)f1, i2 = (int)f2;
        w_[d][0] = xl0 - f0; w_[d][1] = xl1 - f1; w_[d][2] = xl2 - f2;

        unsigned hx0 = (unsigned)i0, hx1 = hx0 + 1u;
        unsigned hy0 = (unsigned)i1 * 2654435761u, hy1 = hy0 + 2654435761u;
        unsigned hz0 = (unsigned)i2 * 805459861u,  hz1 = hz0 + 805459861u;
        int dx0 = 0, dx1 = 0, dy0 = 0, dy1 = 0;
        if (d < 2) {
            dx0 = i0 * np1sq_[d]; dx1 = dx0 + np1sq_[d];
            dy0 = i1 * np1_[d];   dy1 = dy0 + np1_[d];
        }
        #pragma unroll
        for (int c = 0; c < 8; ++c) {
            int o0 = (c >> 2) & 1, o1 = (c >> 1) & 1, o2 = c & 1;
            unsigned h = (o0 ? hx1 : hx0) ^ (o1 ? hy1 : hy0) ^ (o2 ? hz1 : hz0);
            int ind = (int)(h & (TSIZE - 1));
            if (d < 2) {
                int di = (o0 ? dx1 : dx0) + (o1 ? dy1 : dy0) + i2 + o2;
                ind = dense_[d] ? di : ind;
            }
            fe[d][c] = *(const f32x2*)(eb_[d] + (size_t)ind * 2);
        }
    }
}

__global__ __launch_bounds__(256) void nerf_fused(
    const float* __restrict__ x,
    const float* __restrict__ embed,
    const float* __restrict__ dW0, const float* __restrict__ db0,
    const float* __restrict__ dW1, const float* __restrict__ db1,
    const float* __restrict__ cW0, const float* __restrict__ cb0,
    const float* __restrict__ cW1, const float* __restrict__ cb1,
    const float* __restrict__ cW2, const float* __restrict__ cb2,
    float* __restrict__ out, int B, NsParam ns)
{
    const int lane = threadIdx.x & 63;
    const int pt = lane & 15;
    const int q  = lane >> 4;
    const int wavesPerBlock = blockDim.x >> 6;
    const int waveId = blockIdx.x * wavesPerBlock + (threadIdx.x >> 6);
    const int waveStride = gridDim.x * wavesPerBlock;
    const int numTiles = B >> 4;

    Frag wdW0[4][2], wdW1[4], wcW0[4][2], wcW1[4][4], wcW2[4];
    #pragma unroll
    for (int t = 0; t < 4; ++t)
        #pragma unroll
        for (int c = 0; c < 2; ++c)
            wdW0[t][c] = load_wfrag(dW0, 64, 16 * c, q, 16 * t + pt, 32, 64);
    #pragma unroll
    for (int c = 0; c < 4; ++c)
        wdW1[c] = load_wfrag(dW1, 16, 16 * c, q, pt, 64, 16);
    #pragma unroll
    for (int t = 0; t < 4; ++t)
        #pragma unroll
        for (int c = 0; c < 2; ++c)
            wcW0[t][c] = load_wfrag(cW0, 64, 16 * c, q, 16 * t + pt, 19, 64);
    #pragma unroll
    for (int t = 0; t < 4; ++t)
        #pragma unroll
        for (int c = 0; c < 4; ++c)
            wcW1[t][c] = load_wfrag(cW1, 64, 16 * c, q, 16 * t + pt, 64, 64);
    #pragma unroll
    for (int c = 0; c < 4; ++c)
        wcW2[c] = load_wfrag(cW2, 3, 16 * c, q, pt, 64, 3);

    float fn_[4];
    const float* eb_[4];
    int np1_[4], np1sq_[4];
    bool dense_[4];
    #pragma unroll
    for (int d = 0; d < 4; ++d) {
        int base = (d < 2) ? (d) : (8 + (d - 2));
        int lvl = base + 2 * q;
        int n = qsel(q, ns.n[base], ns.n[base + 2], ns.n[base + 4], ns.n[base + 6]);
        fn_[d] = (float)n;
        np1_[d] = n + 1;
        np1sq_[d] = (n + 1) * (n + 1);
        dense_[d] = (ns.densemask >> lvl) & 1u;
        eb_[d] = embed + (size_t)lvl * (TSIZE * 2);
    }

    for (int tile = waveId; tile < numTiles; tile += waveStride) {
        const int ptg = tile * 16 + pt;
        const float* xp = x + (size_t)ptg * 6;
        f32x2 x01 = *(const f32x2*)(xp);
        f32x2 x23 = *(const f32x2*)(xp + 2);
        f32x2 x45 = *(const f32x2*)(xp + 4);
        float vx = x23.y, vy = x45.x, vz = x45.y;

        f32x2 fe[4][8];
        float w_[4][3];
        enc_issue(x01.x, x01.y, x23.x, fn_, eb_, np1_, np1sq_, dense_, fe, w_);

        Frag bf0, bf1;
        #pragma unroll
        for (int d = 0; d < 4; ++d) {
            float w0 = w_[d][0], w1 = w_[d][1], w2 = w_[d][2];
            float u0 = 1.0f - w0, u1 = 1.0f - w1, u2 = 1.0f - w2;
            float wxy[4] = { u0 * u1, u0 * w1, w0 * u1, w0 * w1 };
            float a0 = 0.0f, a1 = 0.0f;
            #pragma unroll
            for (int c = 0; c < 8; ++c) {
                float ww = wxy[c >> 1] * ((c & 1) ? w2 : u2);
                a0 = fmaf(fe[d][c].x, ww, a0);
                a1 = fmaf(fe[d][c].y, ww, a1);
            }
            if (d == 0)      { bf0.v[0] = (_Float16)a0; bf0.v[1] = (_Float16)a1; }
            else if (d == 1) { bf0.v[2] = (_Float16)a0; bf0.v[3] = (_Float16)a1; }
            else if (d == 2) { bf1.v[0] = (_Float16)a0; bf1.v[1] = (_Float16)a1; }
            else             { bf1.v[2] = (_Float16)a0; bf1.v[3] = (_Float16)a1; }
        }

        const float* db0o = db0; const float* db1o = db1;
        const float* cb0o = cb0; const float* cb1o = cb1;
        const float* cb2o = cb2;
        opaque(db0o); opaque(db1o); opaque(cb0o); opaque(cb1o); opaque(cb2o);

        f32x4 acc[4];
        #pragma unroll
        for (int t = 0; t < 4; ++t) {
            acc[t] = *(const f32x4*)(db0o + 16 * t + 4 * q);
            acc[t] = mfma16(wdW0[t][0], bf0, acc[t]);
            acc[t] = mfma16(wdW0[t][1], bf1, acc[t]);
        }
        Frag bh[4];
        #pragma unroll
        for (int c = 0; c < 4; ++c) bh[c] = actpack(acc[c]);

        f32x4 h = *(const f32x4*)(db1o + 4 * q);
        #pragma unroll
        for (int c = 0; c < 4; ++c) h = mfma16(wdW1[c], bh[c], h);

        float dens = sigmoidf(h[0]);
        Frag bcin0, bcin1;
        {
            float a0v = (q == 0) ? dens : fmaxf(h[0], 0.0f);
            bcin0.v[0] = (_Float16)a0v;
            bcin0.v[1] = (_Float16)fmaxf(h[1], 0.0f);
            bcin0.v[2] = (_Float16)fmaxf(h[2], 0.0f);
            bcin0.v[3] = (_Float16)fmaxf(h[3], 0.0f);
            bcin1.v[0] = (_Float16)((q == 0) ? vx : 0.0f);
            bcin1.v[1] = (_Float16)((q == 0) ? vy : 0.0f);
            bcin1.v[2] = (_Float16)((q == 0) ? vz : 0.0f);
            bcin1.v[3] = (_Float16)0.0f;
        }

        #pragma unroll
        for (int t = 0; t < 4; ++t) {
            acc[t] = *(const f32x4*)(cb0o + 16 * t + 4 * q);
            acc[t] = mfma16(wcW0[t][0], bcin0, acc[t]);
            acc[t] = mfma16(wcW0[t][1], bcin1, acc[t]);
        }
        Frag bc[4];
        #pragma unroll
        for (int c = 0; c < 4; ++c) bc[c] = actpack(acc[c]);

        #pragma unroll
        for (int t = 0; t < 4; ++t) {
            acc[t] = *(const f32x4*)(cb1o + 16 * t + 4 * q);
            #pragma unroll
            for (int c = 0; c < 4; ++c) acc[t] = mfma16(wcW1[t][c], bc[c], acc[t]);
        }
        Frag bd[4];
        #pragma unroll
        for (int c = 0; c < 4; ++c) bd[c] = actpack(acc[c]);

        float b0 = cb2o[0], b1 = cb2o[1], b2 = cb2o[2];
        f32x4 fo;
        fo[0] = (q == 0) ? b0 : 0.0f;
        fo[1] = (q == 0) ? b1 : 0.0f;
        fo[2] = (q == 0) ? b2 : 0.0f;
        fo[3] = 0.0f;
        #pragma unroll
        for (int c = 0; c < 4; ++c) fo = mfma16(wcW2[c], bd[c], fo);

        if (q == 0) {
            f32x4 o;
            o[0] = dens;
            o[1] = sigmoidf(fo[0]);
            o[2] = sigmoidf(fo[1]);
            o[3] = sigmoidf(fo[2]);
            *(f32x4*)(out + (size_t)ptg * 4) = o;
        }
    }
}

extern "C" void kernel_launch(void* const* d_in, const int* in_sizes, int n_in,
                              void* d_out, int out_size, void* d_ws, size_t ws_size,
                              hipStream_t stream) {
    const float* x    = (const float*)d_in[0];
    const float* embed= (const float*)d_in[1];
    const float* dW0  = (const float*)d_in[2];
    const float* db0  = (const float*)d_in[3];
    const float* dW1  = (const float*)d_in[4];
    const float* db1  = (const float*)d_in[5];
    const float* cW0  = (const float*)d_in[6];
    const float* cb0  = (const float*)d_in[7];
    const float* cW1  = (const float*)d_in[8];
    const float* cb1  = (const float*)d_in[9];
    const float* cW2  = (const float*)d_in[10];
    const float* cb2  = (const float*)d_in[11];
    float* out = (float*)d_out;

    int B = in_sizes[0] / 6;

    // Replicate numpy's NS computation bit-for-bit (same libm on this host).
    NsParam ns;
    double g = exp((log(512.0) - log(16.0)) / 15.0);
    ns.densemask = 0;
    for (int i = 0; i < NLEVEL; ++i) {
        ns.n[i] = (int)(16.0 * pow(g, (double)i));
        long long np1 = ns.n[i] + 1;
        if (np1 * np1 * np1 <= TSIZE) ns.densemask |= (1u << i);
    }

    size_t wsNeed = (size_t)NLEVEL * (size_t)B * 4;   // fp16x2 per (level,point)
    if (ws_size >= wsNeed && d_ws != nullptr && (B & 15) == 0) {
        unsigned* ws = (unsigned*)d_ws;
        int gridA = (B + CHUNK - 1) / CHUNK;          // 256 at B=2M: 1 block/CU
        nerf_encode<<<gridA, 1024, 0, stream>>>(x, embed, ws, B, ns);
        nerf_mlp<<<2048, 256, 0, stream>>>(x, ws,
            dW0, db0, dW1, db1, cW0, cb0, cW1, cb1, cW2, cb2, out, B);
    } else {
        nerf_fused<<<2048, 256, 0, stream>>>(x, embed,
            dW0, db0, dW1, db1, cW0, cb0, cW1, cb1, cW2, cb2, out, B, ns);
    }
}

// Round 5
// 354.836 us; speedup vs baseline: 2.9968x; 1.0337x over previous
//
#include <hip/hip_runtime.h>
#include <math.h>

#define NLEVEL 16
#define TSIZE 16384
#define CHUNK 4096   // points per encode block (512 threads x 8)

using half4 = __attribute__((ext_vector_type(4))) _Float16;
using f32x4 = __attribute__((ext_vector_type(4))) float;
using f32x2 = __attribute__((ext_vector_type(2))) float;
using u32x2 = __attribute__((ext_vector_type(2))) unsigned;

struct NsParam { int n[NLEVEL]; unsigned densemask; };

union Frag { half4 v; int i[2]; };
union H2 { unsigned u; _Float16 h[2]; };

// A-fragment for mfma_f32_16x16x16f16 of W^T (W row-major [K][N] fp32):
// lane (pt=lane&15, q=lane>>4) holds A[m=out][k=k0+4q+j], j=0..3.
__device__ __forceinline__ Frag load_wfrag(const float* __restrict__ W, int ldn,
                                           int k0, int q, int out,
                                           int kmax, int omax) {
    Frag f;
    #pragma unroll
    for (int j = 0; j < 4; ++j) {
        int k = k0 + 4 * q + j;
        float v = (k < kmax && out < omax) ? W[k * ldn + out] : 0.0f;
        f.v[j] = (_Float16)v;
    }
    return f;
}

__device__ __forceinline__ f32x4 mfma16(const Frag& a, const Frag& b, f32x4 c) {
    return __builtin_amdgcn_mfma_f32_16x16x16f16(a.v, b.v, c, 0, 0, 0);
}

// relu + cvt: C-tile f32x4 -> B-fragment half4 (layouts match for K=16!)
__device__ __forceinline__ Frag actpack(f32x4 a) {
    Frag f;
    #pragma unroll
    for (int j = 0; j < 4; ++j) f.v[j] = (_Float16)fmaxf(a[j], 0.0f);
    return f;
}

__device__ __forceinline__ float sigmoidf(float x) {
    return 1.0f / (1.0f + expf(-x));
}

// q-select among 4 values (q = lane>>4)
__device__ __forceinline__ int qsel(int q, int a, int b, int c, int d) {
    return (q & 2) ? ((q & 1) ? d : c) : ((q & 1) ? b : a);
}

// packed f32x2 -> fp16x2 (RTZ; used only for staging the LDS table copy)
__device__ __forceinline__ unsigned pkrtz(float a, float b) {
    typedef __fp16 fp16x2 __attribute__((ext_vector_type(2)));
    union { fp16x2 h; unsigned u; } r;
    r.h = __builtin_amdgcn_cvt_pkrtz(a, b);
    return r.u;
}

// ============================================================================
// Phase A: hash-grid encode, fp16 level table staged in LDS (64 KB).
// Round-4/5 delta: fp16 table -> random gathers are single-bank ds_read_b32
// (b64 2-bank conflicts halved), 2 blocks/CU so staging of one block
// overlaps gathers of the other. Interpolation via v_fma_mix (f16 source
// operand), so no extra cvt on the consume side.
// ============================================================================

// Compute one point's 8 table indices and ISSUE the 8 LDS gathers.
__device__ __forceinline__ void gather_issue(
    const unsigned* __restrict__ tab,
    float cxp, float cyp, float czp,
    float fn, int np1, int np1sq, int dense,
    unsigned fe[8], float& w0, float& w1, float& w2)
{
    float xl0 = cxp * fn, xl1 = cyp * fn, xl2 = czp * fn;
    float f0 = floorf(xl0), f1 = floorf(xl1), f2 = floorf(xl2);
    int i0 = (int)f0, i1 = (int)f1, i2 = (int)f2;
    w0 = xl0 - f0; w1 = xl1 - f1; w2 = xl2 - f2;
    if (dense) {   // wave-uniform branch (levels 0,1 only)
        int d000 = i0 * np1sq + i1 * np1 + i2;
        #pragma unroll
        for (int c = 0; c < 8; ++c) {
            int o0 = (c >> 2) & 1, o1 = (c >> 1) & 1, o2 = c & 1;
            fe[c] = tab[d000 + (o0 ? np1sq : 0) + (o1 ? np1 : 0) + o2];
        }
    } else {
        unsigned hx0 = (unsigned)i0, hx1 = hx0 + 1u;
        unsigned hy0 = (unsigned)i1 * 2654435761u, hy1 = hy0 + 2654435761u;
        unsigned hz0 = (unsigned)i2 * 805459861u,  hz1 = hz0 + 805459861u;
        #pragma unroll
        for (int c = 0; c < 8; ++c) {
            int o0 = (c >> 2) & 1, o1 = (c >> 1) & 1, o2 = c & 1;
            unsigned h = (o0 ? hx1 : hx0) ^ (o1 ? hy1 : hy0) ^ (o2 ? hz1 : hz0);
            fe[c] = tab[h & (TSIZE - 1)];
        }
    }
}

__global__ __launch_bounds__(512, 4) void nerf_encode(
    const float* __restrict__ x,
    const float* __restrict__ embed,
    unsigned* __restrict__ ws, int B, NsParam ns)
{
    __shared__ unsigned tab[TSIZE];   // fp16x2 entries, 64 KB -> 2 blocks/CU
    const int tid = threadIdx.x;
    const int base = blockIdx.x * CHUNK;

    // Load this block's point coords once; clamp once (reused by all levels).
    float cx[8], cy[8], cz[8];
    #pragma unroll
    for (int p = 0; p < 8; ++p) {
        int idx = base + p * 512 + tid;
        float px = 0.0f, py = 0.0f, pz = 0.0f;
        if (idx < B) {
            const float* xp = x + (size_t)idx * 6;
            f32x2 a = *(const f32x2*)xp;   // 24B stride -> 8B aligned
            px = a.x; py = a.y; pz = xp[2];
        }
        cx[p] = fminf(fmaxf((px + 5.0f) / 10.0f, 0.0f), 0.999999f);
        cy[p] = fminf(fmaxf((py + 5.0f) / 10.0f, 0.0f), 0.999999f);
        cz[p] = fminf(fmaxf((pz + 5.0f) / 10.0f, 0.0f), 0.999999f);
    }

    unsigned stash[8];   // even-level fp16x2 results, paired on odd levels

    for (int l = 0; l < NLEVEL; ++l) {
        __syncthreads();   // WAR: previous level's gathers done before overwrite
        // stage 64 KB fp16 table: 8192 f32x4 (=2 entries each) over 512 threads
        {
            const f32x4* src = (const f32x4*)(embed + (size_t)l * (TSIZE * 2));
            #pragma unroll
            for (int j = 0; j < 16; ++j) {
                f32x4 v = src[tid + 512 * j];
                u32x2 pk;
                pk.x = pkrtz(v.x, v.y);
                pk.y = pkrtz(v.z, v.w);
                *(u32x2*)(tab + 2 * (tid + 512 * j)) = pk;
            }
        }
        __syncthreads();

        const int n = ns.n[l];
        const float fn = (float)n;
        const int np1 = n + 1, np1sq = np1 * np1;
        const int dense = (ns.densemask >> l) & 1;

        // 1-ahead software pipeline: two static buffers, fully unrolled.
        unsigned fe[2][8];
        float w0s[2], w1s[2], w2s[2];
        gather_issue(tab, cx[0], cy[0], cz[0], fn, np1, np1sq, dense,
                     fe[0], w0s[0], w1s[0], w2s[0]);

        #pragma unroll
        for (int p = 0; p < 8; ++p) {
            if (p + 1 < 8)
                gather_issue(tab, cx[p + 1], cy[p + 1], cz[p + 1],
                             fn, np1, np1sq, dense,
                             fe[(p + 1) & 1], w0s[(p + 1) & 1],
                             w1s[(p + 1) & 1], w2s[(p + 1) & 1]);

            float w0 = w0s[p & 1], w1 = w1s[p & 1], w2 = w2s[p & 1];
            float u0 = 1.0f - w0, u1 = 1.0f - w1, u2 = 1.0f - w2;
            float wxy[4] = { u0 * u1, u0 * w1, w0 * u1, w0 * w1 };
            float a0 = 0.0f, a1 = 0.0f;
            #pragma unroll
            for (int c = 0; c < 8; ++c) {
                float ww = wxy[c >> 1] * ((c & 1) ? w2 : u2);
                H2 e; e.u = fe[p & 1][c];
                a0 = fmaf((float)e.h[0], ww, a0);   // v_fma_mix_f32
                a1 = fmaf((float)e.h[1], ww, a1);
            }
            // scalar RTN casts: matches prior rounds' output rounding exactly
            union { _Float16 h2[2]; unsigned u; } pr;
            pr.h2[0] = (_Float16)a0; pr.h2[1] = (_Float16)a1;
            unsigned pk = pr.u;
            if ((l & 1) == 0) {
                stash[p] = pk;
            } else {
                int idx = base + p * 512 + tid;
                if (idx < B) {
                    u32x2 st; st.x = stash[p]; st.y = pk;
                    *((u32x2*)ws + (size_t)(l >> 1) * B + idx) = st;  // cacheable
                }
            }
        }
    }
}

// ============================================================================
// Phase B: MFMA MLP, 32 points per wave-iteration (two independent chains
// sharing resident weights+biases).
// Round-5 deltas: (1) ALL biases VGPR-resident, opaque trick removed -- the
// per-tile bias VMEM loads were issued AFTER the prefetch loads, and
// in-order vmcnt semantics made every bias wait drain the ~900cy prefetch
// (the round-3 stall). Now the ONLY per-iteration VMEM is the prefetch,
// consumed one full iteration later. (2) dual 16-pt chains double MFMA ILP
// and make iteration time > HBM latency so 1-deep prefetch fully hides.
// ============================================================================
struct Pre { Frag f0[2], f1[2]; float vx[2], vy[2], vz[2]; };

__device__ __forceinline__ void prefetch_tile(
    const u32x2* __restrict__ wpl0, const u32x2* __restrict__ wpl1,
    const float* __restrict__ x, int tile32, int pt, Pre& P)
{
    #pragma unroll
    for (int g = 0; g < 2; ++g) {
        int ptg = tile32 * 32 + g * 16 + pt;
        u32x2 a = __builtin_nontemporal_load(wpl0 + ptg);
        u32x2 b = __builtin_nontemporal_load(wpl1 + ptg);
        P.f0[g].i[0] = (int)a.x; P.f0[g].i[1] = (int)a.y;
        P.f1[g].i[0] = (int)b.x; P.f1[g].i[1] = (int)b.y;
        const float* xp = x + (size_t)ptg * 6;
        P.vx[g] = xp[3];
        f32x2 v45 = *(const f32x2*)(xp + 4);
        P.vy[g] = v45.x; P.vz[g] = v45.y;
    }
}

__global__ __launch_bounds__(256) void nerf_mlp(
    const float* __restrict__ x,
    const unsigned* __restrict__ ws,
    const float* __restrict__ dW0, const float* __restrict__ db0,
    const float* __restrict__ dW1, const float* __restrict__ db1,
    const float* __restrict__ cW0, const float* __restrict__ cb0,
    const float* __restrict__ cW1, const float* __restrict__ cb1,
    const float* __restrict__ cW2, const float* __restrict__ cb2,
    float* __restrict__ out, int B)
{
    const int lane = threadIdx.x & 63;
    const int pt = lane & 15;
    const int q  = lane >> 4;
    const int wavesPerBlock = blockDim.x >> 6;
    const int waveId = blockIdx.x * wavesPerBlock + (threadIdx.x >> 6);
    const int waveStride = gridDim.x * wavesPerBlock;
    const int numT = B >> 5;   // 32-pt tiles

    // resident weight A-fragments (80 VGPRs, loaded once)
    Frag wdW0[4][2], wdW1[4], wcW0[4][2], wcW1[4][4], wcW2[4];
    #pragma unroll
    for (int t = 0; t < 4; ++t)
        #pragma unroll
        for (int c = 0; c < 2; ++c)
            wdW0[t][c] = load_wfrag(dW0, 64, 16 * c, q, 16 * t + pt, 32, 64);
    #pragma unroll
    for (int c = 0; c < 4; ++c)
        wdW1[c] = load_wfrag(dW1, 16, 16 * c, q, pt, 64, 16);
    #pragma unroll
    for (int t = 0; t < 4; ++t)
        #pragma unroll
        for (int c = 0; c < 2; ++c)
            wcW0[t][c] = load_wfrag(cW0, 64, 16 * c, q, 16 * t + pt, 19, 64);
    #pragma unroll
    for (int t = 0; t < 4; ++t)
        #pragma unroll
        for (int c = 0; c < 4; ++c)
            wcW1[t][c] = load_wfrag(cW1, 64, 16 * c, q, 16 * t + pt, 64, 64);
    #pragma unroll
    for (int c = 0; c < 4; ++c)
        wcW2[c] = load_wfrag(cW2, 3, 16 * c, q, pt, 64, 3);

    // resident biases (~55 VGPRs, loaded once -- NO per-tile bias VMEM)
    f32x4 Bdb0[4], Bcb0[4], Bcb1[4], Bdb1;
    #pragma unroll
    for (int t = 0; t < 4; ++t) {
        Bdb0[t] = *(const f32x4*)(db0 + 16 * t + 4 * q);
        Bcb0[t] = *(const f32x4*)(cb0 + 16 * t + 4 * q);
        Bcb1[t] = *(const f32x4*)(cb1 + 16 * t + 4 * q);
    }
    Bdb1 = *(const f32x4*)(db1 + 4 * q);
    float c20 = cb2[0], c21 = cb2[1], c22 = cb2[2];

    const u32x2* wpl0 = (const u32x2*)ws + (size_t)q * B;
    const u32x2* wpl1 = (const u32x2*)ws + (size_t)(4 + q) * B;

    int tile = waveId;
    if (tile >= numT) return;

    Pre P;
    prefetch_tile(wpl0, wpl1, x, tile, pt, P);

    for (;;) {
        int next = tile + waveStride;
        bool hasNext = next < numT;

        // consume prefetched registers (waits on loads issued 1 iter ago)
        Frag bf0[2] = { P.f0[0], P.f0[1] };
        Frag bf1[2] = { P.f1[0], P.f1[1] };
        float vx[2] = { P.vx[0], P.vx[1] };
        float vy[2] = { P.vy[0], P.vy[1] };
        float vz[2] = { P.vz[0], P.vz[1] };
        const int ptbase = tile * 32;

        if (hasNext) prefetch_tile(wpl0, wpl1, x, next, pt, P);

        // ---- L0: h64 = dW0^T @ feats (4 out-tiles, K=32) x 2 chains ----
        f32x4 acc[2][4];
        #pragma unroll
        for (int t = 0; t < 4; ++t)
            #pragma unroll
            for (int g = 0; g < 2; ++g) {
                f32x4 a = Bdb0[t];
                a = mfma16(wdW0[t][0], bf0[g], a);
                a = mfma16(wdW0[t][1], bf1[g], a);
                acc[g][t] = a;
            }
        Frag bh[2][4];
        #pragma unroll
        for (int c = 0; c < 4; ++c)
            #pragma unroll
            for (int g = 0; g < 2; ++g) bh[g][c] = actpack(acc[g][c]);

        // ---- L1: h16 = dW1^T @ relu(h64) (1 tile, K=64) ----
        f32x4 h[2] = { Bdb1, Bdb1 };
        #pragma unroll
        for (int c = 0; c < 4; ++c)
            #pragma unroll
            for (int g = 0; g < 2; ++g) h[g] = mfma16(wdW1[c], bh[g][c], h[g]);

        float dens[2];
        Frag bcin0[2], bcin1[2];
        #pragma unroll
        for (int g = 0; g < 2; ++g) {
            dens[g] = sigmoidf(h[g][0]);        // row 0 lives at q==0, reg 0
            float a0v = (q == 0) ? dens[g] : fmaxf(h[g][0], 0.0f);
            bcin0[g].v[0] = (_Float16)a0v;
            bcin0[g].v[1] = (_Float16)fmaxf(h[g][1], 0.0f);
            bcin0[g].v[2] = (_Float16)fmaxf(h[g][2], 0.0f);
            bcin0[g].v[3] = (_Float16)fmaxf(h[g][3], 0.0f);
            // k=16+4q+j: q==0 holds k16..19 = (vx,vy,vz,0) of its own point
            bcin1[g].v[0] = (_Float16)((q == 0) ? vx[g] : 0.0f);
            bcin1[g].v[1] = (_Float16)((q == 0) ? vy[g] : 0.0f);
            bcin1[g].v[2] = (_Float16)((q == 0) ? vz[g] : 0.0f);
            bcin1[g].v[3] = (_Float16)0.0f;
        }

        // ---- L2: c1 = cW0^T @ cin (4 out-tiles, K=19 padded to 32) ----
        #pragma unroll
        for (int t = 0; t < 4; ++t)
            #pragma unroll
            for (int g = 0; g < 2; ++g) {
                f32x4 a = Bcb0[t];
                a = mfma16(wcW0[t][0], bcin0[g], a);
                a = mfma16(wcW0[t][1], bcin1[g], a);
                acc[g][t] = a;
            }
        Frag bc[2][4];
        #pragma unroll
        for (int c = 0; c < 4; ++c)
            #pragma unroll
            for (int g = 0; g < 2; ++g) bc[g][c] = actpack(acc[g][c]);

        // ---- L3: c2 = cW1^T @ relu(c1) (4 out-tiles, K=64) ----
        #pragma unroll
        for (int t = 0; t < 4; ++t)
            #pragma unroll
            for (int g = 0; g < 2; ++g) {
                f32x4 a = Bcb1[t];
                #pragma unroll
                for (int c = 0; c < 4; ++c) a = mfma16(wcW1[t][c], bc[g][c], a);
                acc[g][t] = a;
            }
        Frag bd[2][4];
        #pragma unroll
        for (int c = 0; c < 4; ++c)
            #pragma unroll
            for (int g = 0; g < 2; ++g) bd[g][c] = actpack(acc[g][c]);

        // ---- L4: col = cW2^T @ relu(c2) (rows 0..2, K=64) ----
        f32x4 fo[2];
        #pragma unroll
        for (int g = 0; g < 2; ++g) {
            fo[g][0] = (q == 0) ? c20 : 0.0f;
            fo[g][1] = (q == 0) ? c21 : 0.0f;
            fo[g][2] = (q == 0) ? c22 : 0.0f;
            fo[g][3] = 0.0f;
        }
        #pragma unroll
        for (int c = 0; c < 4; ++c)
            #pragma unroll
            for (int g = 0; g < 2; ++g) fo[g] = mfma16(wcW2[c], bd[g][c], fo[g]);

        if (q == 0) {
            #pragma unroll
            for (int g = 0; g < 2; ++g) {
                f32x4 o;
                o[0] = dens[g];
                o[1] = sigmoidf(fo[g][0]);
                o[2] = sigmoidf(fo[g][1]);
                o[3] = sigmoidf(fo[g][2]);
                __builtin_nontemporal_store(o,
                    (f32x4*)(out + (size_t)(ptbase + g * 16 + pt) * 4));
            }
        }

        if (!hasNext) break;
        tile = next;
    }
}

// ============================================================================
// Fallback: fused single kernel if ws_size is insufficient (unchanged).
// ============================================================================
__device__ __forceinline__ void opaque(const float*& p) {
    asm("" : "+v"(p));
}

__device__ __forceinline__ void enc_issue(
    float px, float py, float pz,
    const float fn_[4], const float* const eb_[4],
    const int np1_[4], const int np1sq_[4], const bool dense_[4],
    f32x2 fe[4][8], float w_[4][3])
{
    float cx = fminf(fmaxf((px + 5.0f) / 10.0f, 0.0f), 0.999999f);
    float cy = fminf(fmaxf((py + 5.0f) / 10.0f, 0.0f), 0.999999f);
    float cz = fminf(fmaxf((pz + 5.0f) / 10.0f, 0.0f), 0.999999f);

    #pragma unroll
    for (int d = 0; d < 4; ++d) {
        float fn = fn_[d];
        float xl0 = cx * fn, xl1 = cy * fn, xl2 = cz * fn;
        float f0 = floorf(xl0), f1 = floorf(xl1), f2 = floorf(xl2);
        int i0 = (int)f0, i1 = (int)f1, i2 = (int)f2;
        w_[d][0] = xl0 - f0; w_[d][1] = xl1 - f1; w_[d][2] = xl2 - f2;

        unsigned hx0 = (unsigned)i0, hx1 = hx0 + 1u;
        unsigned hy0 = (unsigned)i1 * 2654435761u, hy1 = hy0 + 2654435761u;
        unsigned hz0 = (unsigned)i2 * 805459861u,  hz1 = hz0 + 805459861u;
        int dx0 = 0, dx1 = 0, dy0 = 0, dy1 = 0;
        if (d < 2) {
            dx0 = i0 * np1sq_[d]; dx1 = dx0 + np1sq_[d];
            dy0 = i1 * np1_[d];   dy1 = dy0 + np1_[d];
        }
        #pragma unroll
        for (int c = 0; c < 8; ++c) {
            int o0 = (c >> 2) & 1, o1 = (c >> 1) & 1, o2 = c & 1;
            unsigned h = (o0 ? hx1 : hx0) ^ (o1 ? hy1 : hy0) ^ (o2 ? hz1 : hz0);
            int ind = (int)(h & (TSIZE - 1));
            if (d < 2) {
                int di = (o0 ? dx1 : dx0) + (o1 ? dy1 : dy0) + i2 + o2;
                ind = dense_[d] ? di : ind;
            }
            fe[d][c] = *(const f32x2*)(eb_[d] + (size_t)ind * 2);
        }
    }
}

__global__ __launch_bounds__(256) void nerf_fused(
    const float* __restrict__ x,
    const float* __restrict__ embed,
    const float* __restrict__ dW0, const float* __restrict__ db0,
    const float* __restrict__ dW1, const float* __restrict__ db1,
    const float* __restrict__ cW0, const float* __restrict__ cb0,
    const float* __restrict__ cW1, const float* __restrict__ cb1,
    const float* __restrict__ cW2, const float* __restrict__ cb2,
    float* __restrict__ out, int B, NsParam ns)
{
    const int lane = threadIdx.x & 63;
    const int pt = lane & 15;
    const int q  = lane >> 4;
    const int wavesPerBlock = blockDim.x >> 6;
    const int waveId = blockIdx.x * wavesPerBlock + (threadIdx.x >> 6);
    const int waveStride = gridDim.x * wavesPerBlock;
    const int numTiles = B >> 4;

    Frag wdW0[4][2], wdW1[4], wcW0[4][2], wcW1[4][4], wcW2[4];
    #pragma unroll
    for (int t = 0; t < 4; ++t)
        #pragma unroll
        for (int c = 0; c < 2; ++c)
            wdW0[t][c] = load_wfrag(dW0, 64, 16 * c, q, 16 * t + pt, 32, 64);
    #pragma unroll
    for (int c = 0; c < 4; ++c)
        wdW1[c] = load_wfrag(dW1, 16, 16 * c, q, pt, 64, 16);
    #pragma unroll
    for (int t = 0; t < 4; ++t)
        #pragma unroll
        for (int c = 0; c < 2; ++c)
            wcW0[t][c] = load_wfrag(cW0, 64, 16 * c, q, 16 * t + pt, 19, 64);
    #pragma unroll
    for (int t = 0; t < 4; ++t)
        #pragma unroll
        for (int c = 0; c < 4; ++c)
            wcW1[t][c] = load_wfrag(cW1, 64, 16 * c, q, 16 * t + pt, 64, 64);
    #pragma unroll
    for (int c = 0; c < 4; ++c)
        wcW2[c] = load_wfrag(cW2, 3, 16 * c, q, pt, 64, 3);

    float fn_[4];
    const float* eb_[4];
    int np1_[4], np1sq_[4];
    bool dense_[4];
    #pragma unroll
    for (int d = 0; d < 4; ++d) {
        int base = (d < 2) ? (d) : (8 + (d - 2));
        int lvl = base + 2 * q;
        int n = qsel(q, ns.n[base], ns.n[base + 2], ns.n[base + 4], ns.n[base + 6]);
        fn_[d] = (float)n;
        np1_[d] = n + 1;
        np1sq_[d] = (n + 1) * (n + 1);
        dense_[d] = (ns.densemask >> lvl) & 1u;
        eb_[d] = embed + (size_t)lvl * (TSIZE * 2);
    }

    for (int tile = waveId; tile < numTiles; tile += waveStride) {
        const int ptg = tile * 16 + pt;
        const float* xp = x + (size_t)ptg * 6;
        f32x2 x01 = *(const f32x2*)(xp);
        f32x2 x23 = *(const f32x2*)(xp + 2);
        f32x2 x45 = *(const f32x2*)(xp + 4);
        float vx = x23.y, vy = x45.x, vz = x45.y;

        f32x2 fe[4][8];
        float w_[4][3];
        enc_issue(x01.x, x01.y, x23.x, fn_, eb_, np1_, np1sq_, dense_, fe, w_);

        Frag bf0, bf1;
        #pragma unroll
        for (int d = 0; d < 4; ++d) {
            float w0 = w_[d][0], w1 = w_[d][1], w2 = w_[d][2];
            float u0 = 1.0f - w0, u1 = 1.0f - w1, u2 = 1.0f - w2;
            float wxy[4] = { u0 * u1, u0 * w1, w0 * u1, w0 * w1 };
            float a0 = 0.0f, a1 = 0.0f;
            #pragma unroll
            for (int c = 0; c < 8; ++c) {
                float ww = wxy[c >> 1] * ((c & 1) ? w2 : u2);
                a0 = fmaf(fe[d][c].x, ww, a0);
                a1 = fmaf(fe[d][c].y, ww, a1);
            }
            if (d == 0)      { bf0.v[0] = (_Float16)a0; bf0.v[1] = (_Float16)a1; }
            else if (d == 1) { bf0.v[2] = (_Float16)a0; bf0.v[3] = (_Float16)a1; }
            else if (d == 2) { bf1.v[0] = (_Float16)a0; bf1.v[1] = (_Float16)a1; }
            else             { bf1.v[2] = (_Float16)a0; bf1.v[3] = (_Float16)a1; }
        }

        const float* db0o = db0; const float* db1o = db1;
        const float* cb0o = cb0; const float* cb1o = cb1;
        const float* cb2o = cb2;
        opaque(db0o); opaque(db1o); opaque(cb0o); opaque(cb1o); opaque(cb2o);

        f32x4 acc[4];
        #pragma unroll
        for (int t = 0; t < 4; ++t) {
            acc[t] = *(const f32x4*)(db0o + 16 * t + 4 * q);
            acc[t] = mfma16(wdW0[t][0], bf0, acc[t]);
            acc[t] = mfma16(wdW0[t][1], bf1, acc[t]);
        }
        Frag bh[4];
        #pragma unroll
        for (int c = 0; c < 4; ++c) bh[c] = actpack(acc[c]);

        f32x4 h = *(const f32x4*)(db1o + 4 * q);
        #pragma unroll
        for (int c = 0; c < 4; ++c) h = mfma16(wdW1[c], bh[c], h);

        float dens = sigmoidf(h[0]);
        Frag bcin0, bcin1;
        {
            float a0v = (q == 0) ? dens : fmaxf(h[0], 0.0f);
            bcin0.v[0] = (_Float16)a0v;
            bcin0.v[1] = (_Float16)fmaxf(h[1], 0.0f);
            bcin0.v[2] = (_Float16)fmaxf(h[2], 0.0f);
            bcin0.v[3] = (_Float16)fmaxf(h[3], 0.0f);
            bcin1.v[0] = (_Float16)((q == 0) ? vx : 0.0f);
            bcin1.v[1] = (_Float16)((q == 0) ? vy : 0.0f);
            bcin1.v[2] = (_Float16)((q == 0) ? vz : 0.0f);
            bcin1.v[3] = (_Float16)0.0f;
        }

        #pragma unroll
        for (int t = 0; t < 4; ++t) {
            acc[t] = *(const f32x4*)(cb0o + 16 * t + 4 * q);
            acc[t] = mfma16(wcW0[t][0], bcin0, acc[t]);
            acc[t] = mfma16(wcW0[t][1], bcin1, acc[t]);
        }
        Frag bc[4];
        #pragma unroll
        for (int c = 0; c < 4; ++c) bc[c] = actpack(acc[c]);

        #pragma unroll
        for (int t = 0; t < 4; ++t) {
            acc[t] = *(const f32x4*)(cb1o + 16 * t + 4 * q);
            #pragma unroll
            for (int c = 0; c < 4; ++c) acc[t] = mfma16(wcW1[t][c], bc[c], acc[t]);
        }
        Frag bd[4];
        #pragma unroll
        for (int c = 0; c < 4; ++c) bd[c] = actpack(acc[c]);

        float b0 = cb2o[0], b1 = cb2o[1], b2 = cb2o[2];
        f32x4 fo;
        fo[0] = (q == 0) ? b0 : 0.0f;
        fo[1] = (q == 0) ? b1 : 0.0f;
        fo[2] = (q == 0) ? b2 : 0.0f;
        fo[3] = 0.0f;
        #pragma unroll
        for (int c = 0; c < 4; ++c) fo = mfma16(wcW2[c], bd[c], fo);

        if (q == 0) {
            f32x4 o;
            o[0] = dens;
            o[1] = sigmoidf(fo[0]);
            o[2] = sigmoidf(fo[1]);
            o[3] = sigmoidf(fo[2]);
            *(f32x4*)(out + (size_t)ptg * 4) = o;
        }
    }
}

extern "C" void kernel_launch(void* const* d_in, const int* in_sizes, int n_in,
                              void* d_out, int out_size, void* d_ws, size_t ws_size,
                              hipStream_t stream) {
    const float* x    = (const float*)d_in[0];
    const float* embed= (const float*)d_in[1];
    const float* dW0  = (const float*)d_in[2];
    const float* db0  = (const float*)d_in[3];
    const float* dW1  = (const float*)d_in[4];
    const float* db1  = (const float*)d_in[5];
    const float* cW0  = (const float*)d_in[6];
    const float* cb0  = (const float*)d_in[7];
    const float* cW1  = (const float*)d_in[8];
    const float* cb1  = (const float*)d_in[9];
    const float* cW2  = (const float*)d_in[10];
    const float* cb2  = (const float*)d_in[11];
    float* out = (float*)d_out;

    int B = in_sizes[0] / 6;

    // Replicate numpy's NS computation bit-for-bit (same libm on this host).
    NsParam ns;
    double g = exp((log(512.0) - log(16.0)) / 15.0);
    ns.densemask = 0;
    for (int i = 0; i < NLEVEL; ++i) {
        ns.n[i] = (int)(16.0 * pow(g, (double)i));
        long long np1 = ns.n[i] + 1;
        if (np1 * np1 * np1 <= TSIZE) ns.densemask |= (1u << i);
    }

    size_t wsNeed = (size_t)NLEVEL * (size_t)B * 4;   // fp16x2 per (level,point)
    if (ws_size >= wsNeed && d_ws != nullptr && (B & 31) == 0) {
        unsigned* ws = (unsigned*)d_ws;
        int gridA = (B + CHUNK - 1) / CHUNK;          // 512 at B=2M: 2 blocks/CU
        nerf_encode<<<gridA, 512, 0, stream>>>(x, embed, ws, B, ns);
        nerf_mlp<<<2048, 256, 0, stream>>>(x, ws,
            dW0, db0, dW1, db1, cW0, cb0, cW1, cb1, cW2, cb2, out, B);
    } else {
        nerf_fused<<<2048, 256, 0, stream>>>(x, embed,
            dW0, db0, dW1, db1, cW0, cb0, cW1, cb1, cW2, cb2, out, B, ns);
    }
}

// Round 6
// 314.934 us; speedup vs baseline: 3.3765x; 1.1267x over previous
//
#include <hip/hip_runtime.h>
#include <math.h>

#define NLEVEL 16
#define TSIZE 16384
#define CHUNK 4096   // points per encode block (1024 threads x 4)

using half4 = __attribute__((ext_vector_type(4))) _Float16;
using f32x4 = __attribute__((ext_vector_type(4))) float;
using f32x2 = __attribute__((ext_vector_type(2))) float;
using u32x2 = __attribute__((ext_vector_type(2))) unsigned;
typedef __fp16 hv2 __attribute__((ext_vector_type(2)));

struct NsParam { int n[NLEVEL]; unsigned densemask; };

union Frag { half4 v; int i[2]; };
union Hu { unsigned u; hv2 h; };

// A-fragment for mfma_f32_16x16x16f16 of W^T (W row-major [K][N] fp32):
// lane (pt=lane&15, q=lane>>4) holds A[m=out][k=k0+4q+j], j=0..3.
__device__ __forceinline__ Frag load_wfrag(const float* __restrict__ W, int ldn,
                                           int k0, int q, int out,
                                           int kmax, int omax) {
    Frag f;
    #pragma unroll
    for (int j = 0; j < 4; ++j) {
        int k = k0 + 4 * q + j;
        float v = (k < kmax && out < omax) ? W[k * ldn + out] : 0.0f;
        f.v[j] = (_Float16)v;
    }
    return f;
}

__device__ __forceinline__ f32x4 mfma16(const Frag& a, const Frag& b, f32x4 c) {
    return __builtin_amdgcn_mfma_f32_16x16x16f16(a.v, b.v, c, 0, 0, 0);
}

// relu + cvt: C-tile f32x4 -> B-fragment half4 (layouts match for K=16!)
__device__ __forceinline__ Frag actpack(f32x4 a) {
    Frag f;
    #pragma unroll
    for (int j = 0; j < 4; ++j) f.v[j] = (_Float16)fmaxf(a[j], 0.0f);
    return f;
}

__device__ __forceinline__ float sigmoidf(float x) {
    return 1.0f / (1.0f + expf(-x));
}

// q-select among 4 values (q = lane>>4)
__device__ __forceinline__ int qsel(int q, int a, int b, int c, int d) {
    return (q & 2) ? ((q & 1) ? d : c) : ((q & 1) ? b : a);
}

// packed f32x2 -> fp16x2 (RTZ)
__device__ __forceinline__ unsigned pkrtz(float a, float b) {
    union { hv2 h; unsigned u; } r;
    r.h = __builtin_amdgcn_cvt_pkrtz(a, b);
    return r.u;
}

__device__ __forceinline__ hv2 splath(float w) {
    Hu r; r.u = pkrtz(w, w); return r.h;
}

// packed-fp16 lerp: a + w*(b-a)   (one v_pk_sub + one v_pk_fma)
__device__ __forceinline__ hv2 hlerp(hv2 a, hv2 b, hv2 w) {
    return (hv2)((b - a) * w + a);
}

// ============================================================================
// Phase A: hash-grid encode, fp16 level table staged in LDS (64 KB).
// Round-6 deltas: (1) 1024-thread blocks, 4 pts/thread -> 32 waves/CU (100%
// occupancy, was 45%): VALU of some waves overlaps LDS-conflict stalls of
// others (the round-5 counters showed 46% VALU + ~30% bank-conflict cycles,
// neither pipe saturated). (2) packed-fp16 trilinear lerp TREE (7 lerps =
// 14 v_pk ops + 3 splats) replaces 8-corner weighted sum (~24 VALU) and the
// result is already fp16x2 -> output pack free.
// ============================================================================

// Compute one point's 8 table indices and ISSUE the 8 LDS gathers.
__device__ __forceinline__ void gather_issue(
    const unsigned* __restrict__ tab,
    float cxp, float cyp, float czp,
    float fn, int np1, int np1sq, int dense,
    unsigned fe[8], float& w0, float& w1, float& w2)
{
    float xl0 = cxp * fn, xl1 = cyp * fn, xl2 = czp * fn;
    float f0 = floorf(xl0), f1 = floorf(xl1), f2 = floorf(xl2);
    int i0 = (int)f0, i1 = (int)f1, i2 = (int)f2;
    w0 = xl0 - f0; w1 = xl1 - f1; w2 = xl2 - f2;
    if (dense) {   // wave-uniform branch (levels 0,1 only)
        int d000 = i0 * np1sq + i1 * np1 + i2;
        #pragma unroll
        for (int c = 0; c < 8; ++c) {
            int o0 = (c >> 2) & 1, o1 = (c >> 1) & 1, o2 = c & 1;
            fe[c] = tab[d000 + (o0 ? np1sq : 0) + (o1 ? np1 : 0) + o2];
        }
    } else {
        unsigned hx0 = (unsigned)i0, hx1 = hx0 + 1u;
        unsigned hy0 = (unsigned)i1 * 2654435761u, hy1 = hy0 + 2654435761u;
        unsigned hz0 = (unsigned)i2 * 805459861u,  hz1 = hz0 + 805459861u;
        #pragma unroll
        for (int c = 0; c < 8; ++c) {
            int o0 = (c >> 2) & 1, o1 = (c >> 1) & 1, o2 = c & 1;
            unsigned h = (o0 ? hx1 : hx0) ^ (o1 ? hy1 : hy0) ^ (o2 ? hz1 : hz0);
            fe[c] = tab[h & (TSIZE - 1)];
        }
    }
}

// fp16 trilinear tree-lerp over the 8 gathered corners -> fp16x2 feature pair
__device__ __forceinline__ unsigned interp_tree(
    const unsigned fe[8], float w0, float w1, float w2)
{
    hv2 W0 = splath(w0), W1 = splath(w1), W2 = splath(w2);
    Hu a, b;
    a.u = fe[0]; b.u = fe[1]; hv2 g00 = hlerp(a.h, b.h, W2);
    a.u = fe[2]; b.u = fe[3]; hv2 g01 = hlerp(a.h, b.h, W2);
    a.u = fe[4]; b.u = fe[5]; hv2 g10 = hlerp(a.h, b.h, W2);
    a.u = fe[6]; b.u = fe[7]; hv2 g11 = hlerp(a.h, b.h, W2);
    hv2 gy0 = hlerp(g00, g01, W1);
    hv2 gy1 = hlerp(g10, g11, W1);
    Hu r; r.h = hlerp(gy0, gy1, W0);
    return r.u;
}

__global__ __launch_bounds__(1024, 8) void nerf_encode(
    const float* __restrict__ x,
    const float* __restrict__ embed,
    unsigned* __restrict__ ws, int B, NsParam ns)
{
    __shared__ unsigned tab[TSIZE];   // fp16x2 entries, 64 KB -> 2 blocks/CU
    const int tid = threadIdx.x;
    const int base = blockIdx.x * CHUNK;

    // Load this block's point coords once; clamp once (reused by all levels).
    float cx[4], cy[4], cz[4];
    #pragma unroll
    for (int p = 0; p < 4; ++p) {
        int idx = base + p * 1024 + tid;
        float px = 0.0f, py = 0.0f, pz = 0.0f;
        if (idx < B) {
            const float* xp = x + (size_t)idx * 6;
            f32x2 a = *(const f32x2*)xp;   // 24B stride -> 8B aligned
            px = a.x; py = a.y; pz = xp[2];
        }
        cx[p] = fminf(fmaxf((px + 5.0f) / 10.0f, 0.0f), 0.999999f);
        cy[p] = fminf(fmaxf((py + 5.0f) / 10.0f, 0.0f), 0.999999f);
        cz[p] = fminf(fmaxf((pz + 5.0f) / 10.0f, 0.0f), 0.999999f);
    }

    unsigned stash[4];   // even-level fp16x2 results, paired on odd levels

    for (int l = 0; l < NLEVEL; ++l) {
        __syncthreads();   // WAR: previous level's gathers done before overwrite
        // stage 64 KB fp16 table: 8192 f32x4 (=2 entries each) over 1024 thr
        {
            const f32x4* src = (const f32x4*)(embed + (size_t)l * (TSIZE * 2));
            #pragma unroll
            for (int j = 0; j < 8; ++j) {
                f32x4 v = src[tid + 1024 * j];
                u32x2 pk;
                pk.x = pkrtz(v.x, v.y);
                pk.y = pkrtz(v.z, v.w);
                *(u32x2*)(tab + 2 * (tid + 1024 * j)) = pk;
            }
        }
        __syncthreads();

        const int n = ns.n[l];
        const float fn = (float)n;
        const int np1 = n + 1, np1sq = np1 * np1;
        const int dense = (ns.densemask >> l) & 1;

        // 1-ahead software pipeline: two static buffers, fully unrolled.
        unsigned fe[2][8];
        float w0s[2], w1s[2], w2s[2];
        gather_issue(tab, cx[0], cy[0], cz[0], fn, np1, np1sq, dense,
                     fe[0], w0s[0], w1s[0], w2s[0]);

        #pragma unroll
        for (int p = 0; p < 4; ++p) {
            if (p + 1 < 4)
                gather_issue(tab, cx[p + 1], cy[p + 1], cz[p + 1],
                             fn, np1, np1sq, dense,
                             fe[(p + 1) & 1], w0s[(p + 1) & 1],
                             w1s[(p + 1) & 1], w2s[(p + 1) & 1]);

            unsigned pk = interp_tree(fe[p & 1], w0s[p & 1], w1s[p & 1],
                                      w2s[p & 1]);
            if ((l & 1) == 0) {
                stash[p] = pk;
            } else {
                int idx = base + p * 1024 + tid;
                if (idx < B) {
                    u32x2 st; st.x = stash[p]; st.y = pk;
                    *((u32x2*)ws + (size_t)(l >> 1) * B + idx) = st;  // cacheable
                }
            }
        }
    }
}

// ============================================================================
// Phase B: MFMA MLP, 32 points per wave-iteration (two independent chains
// sharing resident weights+biases). All biases VGPR-resident; only
// per-iteration VMEM is the 1-deep cross-tile prefetch (vmcnt-ordering fix,
// round 5). Round-6 delta: s_setprio(1) around the MFMA chain (waves are
// independent -> priority arbitration can keep the matrix pipe fed).
// ============================================================================
struct Pre { Frag f0[2], f1[2]; float vx[2], vy[2], vz[2]; };

__device__ __forceinline__ void prefetch_tile(
    const u32x2* __restrict__ wpl0, const u32x2* __restrict__ wpl1,
    const float* __restrict__ x, int tile32, int pt, Pre& P)
{
    #pragma unroll
    for (int g = 0; g < 2; ++g) {
        int ptg = tile32 * 32 + g * 16 + pt;
        u32x2 a = __builtin_nontemporal_load(wpl0 + ptg);
        u32x2 b = __builtin_nontemporal_load(wpl1 + ptg);
        P.f0[g].i[0] = (int)a.x; P.f0[g].i[1] = (int)a.y;
        P.f1[g].i[0] = (int)b.x; P.f1[g].i[1] = (int)b.y;
        const float* xp = x + (size_t)ptg * 6;
        P.vx[g] = xp[3];
        f32x2 v45 = *(const f32x2*)(xp + 4);
        P.vy[g] = v45.x; P.vz[g] = v45.y;
    }
}

__global__ __launch_bounds__(256) void nerf_mlp(
    const float* __restrict__ x,
    const unsigned* __restrict__ ws,
    const float* __restrict__ dW0, const float* __restrict__ db0,
    const float* __restrict__ dW1, const float* __restrict__ db1,
    const float* __restrict__ cW0, const float* __restrict__ cb0,
    const float* __restrict__ cW1, const float* __restrict__ cb1,
    const float* __restrict__ cW2, const float* __restrict__ cb2,
    float* __restrict__ out, int B)
{
    const int lane = threadIdx.x & 63;
    const int pt = lane & 15;
    const int q  = lane >> 4;
    const int wavesPerBlock = blockDim.x >> 6;
    const int waveId = blockIdx.x * wavesPerBlock + (threadIdx.x >> 6);
    const int waveStride = gridDim.x * wavesPerBlock;
    const int numT = B >> 5;   // 32-pt tiles

    // resident weight A-fragments (80 VGPRs, loaded once)
    Frag wdW0[4][2], wdW1[4], wcW0[4][2], wcW1[4][4], wcW2[4];
    #pragma unroll
    for (int t = 0; t < 4; ++t)
        #pragma unroll
        for (int c = 0; c < 2; ++c)
            wdW0[t][c] = load_wfrag(dW0, 64, 16 * c, q, 16 * t + pt, 32, 64);
    #pragma unroll
    for (int c = 0; c < 4; ++c)
        wdW1[c] = load_wfrag(dW1, 16, 16 * c, q, pt, 64, 16);
    #pragma unroll
    for (int t = 0; t < 4; ++t)
        #pragma unroll
        for (int c = 0; c < 2; ++c)
            wcW0[t][c] = load_wfrag(cW0, 64, 16 * c, q, 16 * t + pt, 19, 64);
    #pragma unroll
    for (int t = 0; t < 4; ++t)
        #pragma unroll
        for (int c = 0; c < 4; ++c)
            wcW1[t][c] = load_wfrag(cW1, 64, 16 * c, q, 16 * t + pt, 64, 64);
    #pragma unroll
    for (int c = 0; c < 4; ++c)
        wcW2[c] = load_wfrag(cW2, 3, 16 * c, q, pt, 64, 3);

    // resident biases (~55 VGPRs, loaded once -- NO per-tile bias VMEM)
    f32x4 Bdb0[4], Bcb0[4], Bcb1[4], Bdb1;
    #pragma unroll
    for (int t = 0; t < 4; ++t) {
        Bdb0[t] = *(const f32x4*)(db0 + 16 * t + 4 * q);
        Bcb0[t] = *(const f32x4*)(cb0 + 16 * t + 4 * q);
        Bcb1[t] = *(const f32x4*)(cb1 + 16 * t + 4 * q);
    }
    Bdb1 = *(const f32x4*)(db1 + 4 * q);
    float c20 = cb2[0], c21 = cb2[1], c22 = cb2[2];

    const u32x2* wpl0 = (const u32x2*)ws + (size_t)q * B;
    const u32x2* wpl1 = (const u32x2*)ws + (size_t)(4 + q) * B;

    int tile = waveId;
    if (tile >= numT) return;

    Pre P;
    prefetch_tile(wpl0, wpl1, x, tile, pt, P);

    for (;;) {
        int next = tile + waveStride;
        bool hasNext = next < numT;

        // consume prefetched registers (waits on loads issued 1 iter ago)
        Frag bf0[2] = { P.f0[0], P.f0[1] };
        Frag bf1[2] = { P.f1[0], P.f1[1] };
        float vx[2] = { P.vx[0], P.vx[1] };
        float vy[2] = { P.vy[0], P.vy[1] };
        float vz[2] = { P.vz[0], P.vz[1] };
        const int ptbase = tile * 32;

        if (hasNext) prefetch_tile(wpl0, wpl1, x, next, pt, P);

        __builtin_amdgcn_s_setprio(1);

        // ---- L0: h64 = dW0^T @ feats (4 out-tiles, K=32) x 2 chains ----
        f32x4 acc[2][4];
        #pragma unroll
        for (int t = 0; t < 4; ++t)
            #pragma unroll
            for (int g = 0; g < 2; ++g) {
                f32x4 a = Bdb0[t];
                a = mfma16(wdW0[t][0], bf0[g], a);
                a = mfma16(wdW0[t][1], bf1[g], a);
                acc[g][t] = a;
            }
        Frag bh[2][4];
        #pragma unroll
        for (int c = 0; c < 4; ++c)
            #pragma unroll
            for (int g = 0; g < 2; ++g) bh[g][c] = actpack(acc[g][c]);

        // ---- L1: h16 = dW1^T @ relu(h64) (1 tile, K=64) ----
        f32x4 h[2] = { Bdb1, Bdb1 };
        #pragma unroll
        for (int c = 0; c < 4; ++c)
            #pragma unroll
            for (int g = 0; g < 2; ++g) h[g] = mfma16(wdW1[c], bh[g][c], h[g]);

        float dens[2];
        Frag bcin0[2], bcin1[2];
        #pragma unroll
        for (int g = 0; g < 2; ++g) {
            dens[g] = sigmoidf(h[g][0]);        // row 0 lives at q==0, reg 0
            float a0v = (q == 0) ? dens[g] : fmaxf(h[g][0], 0.0f);
            bcin0[g].v[0] = (_Float16)a0v;
            bcin0[g].v[1] = (_Float16)fmaxf(h[g][1], 0.0f);
            bcin0[g].v[2] = (_Float16)fmaxf(h[g][2], 0.0f);
            bcin0[g].v[3] = (_Float16)fmaxf(h[g][3], 0.0f);
            // k=16+4q+j: q==0 holds k16..19 = (vx,vy,vz,0) of its own point
            bcin1[g].v[0] = (_Float16)((q == 0) ? vx[g] : 0.0f);
            bcin1[g].v[1] = (_Float16)((q == 0) ? vy[g] : 0.0f);
            bcin1[g].v[2] = (_Float16)((q == 0) ? vz[g] : 0.0f);
            bcin1[g].v[3] = (_Float16)0.0f;
        }

        // ---- L2: c1 = cW0^T @ cin (4 out-tiles, K=19 padded to 32) ----
        #pragma unroll
        for (int t = 0; t < 4; ++t)
            #pragma unroll
            for (int g = 0; g < 2; ++g) {
                f32x4 a = Bcb0[t];
                a = mfma16(wcW0[t][0], bcin0[g], a);
                a = mfma16(wcW0[t][1], bcin1[g], a);
                acc[g][t] = a;
            }
        Frag bc[2][4];
        #pragma unroll
        for (int c = 0; c < 4; ++c)
            #pragma unroll
            for (int g = 0; g < 2; ++g) bc[g][c] = actpack(acc[g][c]);

        // ---- L3: c2 = cW1^T @ relu(c1) (4 out-tiles, K=64) ----
        #pragma unroll
        for (int t = 0; t < 4; ++t)
            #pragma unroll
            for (int g = 0; g < 2; ++g) {
                f32x4 a = Bcb1[t];
                #pragma unroll
                for (int c = 0; c < 4; ++c) a = mfma16(wcW1[t][c], bc[g][c], a);
                acc[g][t] = a;
            }
        Frag bd[2][4];
        #pragma unroll
        for (int c = 0; c < 4; ++c)
            #pragma unroll
            for (int g = 0; g < 2; ++g) bd[g][c] = actpack(acc[g][c]);

        // ---- L4: col = cW2^T @ relu(c2) (rows 0..2, K=64) ----
        f32x4 fo[2];
        #pragma unroll
        for (int g = 0; g < 2; ++g) {
            fo[g][0] = (q == 0) ? c20 : 0.0f;
            fo[g][1] = (q == 0) ? c21 : 0.0f;
            fo[g][2] = (q == 0) ? c22 : 0.0f;
            fo[g][3] = 0.0f;
        }
        #pragma unroll
        for (int c = 0; c < 4; ++c)
            #pragma unroll
            for (int g = 0; g < 2; ++g) fo[g] = mfma16(wcW2[c], bd[g][c], fo[g]);

        __builtin_amdgcn_s_setprio(0);

        if (q == 0) {
            #pragma unroll
            for (int g = 0; g < 2; ++g) {
                f32x4 o;
                o[0] = dens[g];
                o[1] = sigmoidf(fo[g][0]);
                o[2] = sigmoidf(fo[g][1]);
                o[3] = sigmoidf(fo[g][2]);
                __builtin_nontemporal_store(o,
                    (f32x4*)(out + (size_t)(ptbase + g * 16 + pt) * 4));
            }
        }

        if (!hasNext) break;
        tile = next;
    }
}

// ============================================================================
// Fallback: fused single kernel if ws_size is insufficient (unchanged).
// ============================================================================
__device__ __forceinline__ void opaque(const float*& p) {
    asm("" : "+v"(p));
}

__device__ __forceinline__ void enc_issue(
    float px, float py, float pz,
    const float fn_[4], const float* const eb_[4],
    const int np1_[4], const int np1sq_[4], const bool dense_[4],
    f32x2 fe[4][8], float w_[4][3])
{
    float cx = fminf(fmaxf((px + 5.0f) / 10.0f, 0.0f), 0.999999f);
    float cy = fminf(fmaxf((py + 5.0f) / 10.0f, 0.0f), 0.999999f);
    float cz = fminf(fmaxf((pz + 5.0f) / 10.0f, 0.0f), 0.999999f);

    #pragma unroll
    for (int d = 0; d < 4; ++d) {
        float fn = fn_[d];
        float xl0 = cx * fn, xl1 = cy * fn, xl2 = cz * fn;
        float f0 = floorf(xl0), f1 = floorf(xl1), f2 = floorf(xl2);
        int i0 = (int)f0, i1 = (int)f1, i2 = (int)f2;
        w_[d][0] = xl0 - f0; w_[d][1] = xl1 - f1; w_[d][2] = xl2 - f2;

        unsigned hx0 = (unsigned)i0, hx1 = hx0 + 1u;
        unsigned hy0 = (unsigned)i1 * 2654435761u, hy1 = hy0 + 2654435761u;
        unsigned hz0 = (unsigned)i2 * 805459861u,  hz1 = hz0 + 805459861u;
        int dx0 = 0, dx1 = 0, dy0 = 0, dy1 = 0;
        if (d < 2) {
            dx0 = i0 * np1sq_[d]; dx1 = dx0 + np1sq_[d];
            dy0 = i1 * np1_[d];   dy1 = dy0 + np1_[d];
        }
        #pragma unroll
        for (int c = 0; c < 8; ++c) {
            int o0 = (c >> 2) & 1, o1 = (c >> 1) & 1, o2 = c & 1;
            unsigned h = (o0 ? hx1 : hx0) ^ (o1 ? hy1 : hy0) ^ (o2 ? hz1 : hz0);
            int ind = (int)(h & (TSIZE - 1));
            if (d < 2) {
                int di = (o0 ? dx1 : dx0) + (o1 ? dy1 : dy0) + i2 + o2;
                ind = dense_[d] ? di : ind;
            }
            fe[d][c] = *(const f32x2*)(eb_[d] + (size_t)ind * 2);
        }
    }
}

__global__ __launch_bounds__(256) void nerf_fused(
    const float* __restrict__ x,
    const float* __restrict__ embed,
    const float* __restrict__ dW0, const float* __restrict__ db0,
    const float* __restrict__ dW1, const float* __restrict__ db1,
    const float* __restrict__ cW0, const float* __restrict__ cb0,
    const float* __restrict__ cW1, const float* __restrict__ cb1,
    const float* __restrict__ cW2, const float* __restrict__ cb2,
    float* __restrict__ out, int B, NsParam ns)
{
    const int lane = threadIdx.x & 63;
    const int pt = lane & 15;
    const int q  = lane >> 4;
    const int wavesPerBlock = blockDim.x >> 6;
    const int waveId = blockIdx.x * wavesPerBlock + (threadIdx.x >> 6);
    const int waveStride = gridDim.x * wavesPerBlock;
    const int numTiles = B >> 4;

    Frag wdW0[4][2], wdW1[4], wcW0[4][2], wcW1[4][4], wcW2[4];
    #pragma unroll
    for (int t = 0; t < 4; ++t)
        #pragma unroll
        for (int c = 0; c < 2; ++c)
            wdW0[t][c] = load_wfrag(dW0, 64, 16 * c, q, 16 * t + pt, 32, 64);
    #pragma unroll
    for (int c = 0; c < 4; ++c)
        wdW1[c] = load_wfrag(dW1, 16, 16 * c, q, pt, 64, 16);
    #pragma unroll
    for (int t = 0; t < 4; ++t)
        #pragma unroll
        for (int c = 0; c < 2; ++c)
            wcW0[t][c] = load_wfrag(cW0, 64, 16 * c, q, 16 * t + pt, 19, 64);
    #pragma unroll
    for (int t = 0; t < 4; ++t)
        #pragma unroll
        for (int c = 0; c < 4; ++c)
            wcW1[t][c] = load_wfrag(cW1, 64, 16 * c, q, 16 * t + pt, 64, 64);
    #pragma unroll
    for (int c = 0; c < 4; ++c)
        wcW2[c] = load_wfrag(cW2, 3, 16 * c, q, pt, 64, 3);

    float fn_[4];
    const float* eb_[4];
    int np1_[4], np1sq_[4];
    bool dense_[4];
    #pragma unroll
    for (int d = 0; d < 4; ++d) {
        int base = (d < 2) ? (d) : (8 + (d - 2));
        int lvl = base + 2 * q;
        int n = qsel(q, ns.n[base], ns.n[base + 2], ns.n[base + 4], ns.n[base + 6]);
        fn_[d] = (float)n;
        np1_[d] = n + 1;
        np1sq_[d] = (n + 1) * (n + 1);
        dense_[d] = (ns.densemask >> lvl) & 1u;
        eb_[d] = embed + (size_t)lvl * (TSIZE * 2);
    }

    for (int tile = waveId; tile < numTiles; tile += waveStride) {
        const int ptg = tile * 16 + pt;
        const float* xp = x + (size_t)ptg * 6;
        f32x2 x01 = *(const f32x2*)(xp);
        f32x2 x23 = *(const f32x2*)(xp + 2);
        f32x2 x45 = *(const f32x2*)(xp + 4);
        float vx = x23.y, vy = x45.x, vz = x45.y;

        f32x2 fe[4][8];
        float w_[4][3];
        enc_issue(x01.x, x01.y, x23.x, fn_, eb_, np1_, np1sq_, dense_, fe, w_);

        Frag bf0, bf1;
        #pragma unroll
        for (int d = 0; d < 4; ++d) {
            float w0 = w_[d][0], w1 = w_[d][1], w2 = w_[d][2];
            float u0 = 1.0f - w0, u1 = 1.0f - w1, u2 = 1.0f - w2;
            float wxy[4] = { u0 * u1, u0 * w1, w0 * u1, w0 * w1 };
            float a0 = 0.0f, a1 = 0.0f;
            #pragma unroll
            for (int c = 0; c < 8; ++c) {
                float ww = wxy[c >> 1] * ((c & 1) ? w2 : u2);
                a0 = fmaf(fe[d][c].x, ww, a0);
                a1 = fmaf(fe[d][c].y, ww, a1);
            }
            if (d == 0)      { bf0.v[0] = (_Float16)a0; bf0.v[1] = (_Float16)a1; }
            else if (d == 1) { bf0.v[2] = (_Float16)a0; bf0.v[3] = (_Float16)a1; }
            else if (d == 2) { bf1.v[0] = (_Float16)a0; bf1.v[1] = (_Float16)a1; }
            else             { bf1.v[2] = (_Float16)a0; bf1.v[3] = (_Float16)a1; }
        }

        const float* db0o = db0; const float* db1o = db1;
        const float* cb0o = cb0; const float* cb1o = cb1;
        const float* cb2o = cb2;
        opaque(db0o); opaque(db1o); opaque(cb0o); opaque(cb1o); opaque(cb2o);

        f32x4 acc[4];
        #pragma unroll
        for (int t = 0; t < 4; ++t) {
            acc[t] = *(const f32x4*)(db0o + 16 * t + 4 * q);
            acc[t] = mfma16(wdW0[t][0], bf0, acc[t]);
            acc[t] = mfma16(wdW0[t][1], bf1, acc[t]);
        }
        Frag bh[4];
        #pragma unroll
        for (int c = 0; c < 4; ++c) bh[c] = actpack(acc[c]);

        f32x4 h = *(const f32x4*)(db1o + 4 * q);
        #pragma unroll
        for (int c = 0; c < 4; ++c) h = mfma16(wdW1[c], bh[c], h);

        float dens = sigmoidf(h[0]);
        Frag bcin0, bcin1;
        {
            float a0v = (q == 0) ? dens : fmaxf(h[0], 0.0f);
            bcin0.v[0] = (_Float16)a0v;
            bcin0.v[1] = (_Float16)fmaxf(h[1], 0.0f);
            bcin0.v[2] = (_Float16)fmaxf(h[2], 0.0f);
            bcin0.v[3] = (_Float16)fmaxf(h[3], 0.0f);
            bcin1.v[0] = (_Float16)((q == 0) ? vx : 0.0f);
            bcin1.v[1] = (_Float16)((q == 0) ? vy : 0.0f);
            bcin1.v[2] = (_Float16)((q == 0) ? vz : 0.0f);
            bcin1.v[3] = (_Float16)0.0f;
        }

        #pragma unroll
        for (int t = 0; t < 4; ++t) {
            acc[t] = *(const f32x4*)(cb0o + 16 * t + 4 * q);
            acc[t] = mfma16(wcW0[t][0], bcin0, acc[t]);
            acc[t] = mfma16(wcW0[t][1], bcin1, acc[t]);
        }
        Frag bc[4];
        #pragma unroll
        for (int c = 0; c < 4; ++c) bc[c] = actpack(acc[c]);

        #pragma unroll
        for (int t = 0; t < 4; ++t) {
            acc[t] = *(const f32x4*)(cb1o + 16 * t + 4 * q);
            #pragma unroll
            for (int c = 0; c < 4; ++c) acc[t] = mfma16(wcW1[t][c], bc[c], acc[t]);
        }
        Frag bd[4];
        #pragma unroll
        for (int c = 0; c < 4; ++c) bd[c] = actpack(acc[c]);

        float b0 = cb2o[0], b1 = cb2o[1], b2 = cb2o[2];
        f32x4 fo;
        fo[0] = (q == 0) ? b0 : 0.0f;
        fo[1] = (q == 0) ? b1 : 0.0f;
        fo[2] = (q == 0) ? b2 : 0.0f;
        fo[3] = 0.0f;
        #pragma unroll
        for (int c = 0; c < 4; ++c) fo = mfma16(wcW2[c], bd[c], fo);

        if (q == 0) {
            f32x4 o;
            o[0] = dens;
            o[1] = sigmoidf(fo[0]);
            o[2] = sigmoidf(fo[1]);
            o[3] = sigmoidf(fo[2]);
            *(f32x4*)(out + (size_t)ptg * 4) = o;
        }
    }
}

extern "C" void kernel_launch(void* const* d_in, const int* in_sizes, int n_in,
                              void* d_out, int out_size, void* d_ws, size_t ws_size,
                              hipStream_t stream) {
    const float* x    = (const float*)d_in[0];
    const float* embed= (const float*)d_in[1];
    const float* dW0  = (const float*)d_in[2];
    const float* db0  = (const float*)d_in[3];
    const float* dW1  = (const float*)d_in[4];
    const float* db1  = (const float*)d_in[5];
    const float* cW0  = (const float*)d_in[6];
    const float* cb0  = (const float*)d_in[7];
    const float* cW1  = (const float*)d_in[8];
    const float* cb1  = (const float*)d_in[9];
    const float* cW2  = (const float*)d_in[10];
    const float* cb2  = (const float*)d_in[11];
    float* out = (float*)d_out;

    int B = in_sizes[0] / 6;

    // Replicate numpy's NS computation bit-for-bit (same libm on this host).
    NsParam ns;
    double g = exp((log(512.0) - log(16.0)) / 15.0);
    ns.densemask = 0;
    for (int i = 0; i < NLEVEL; ++i) {
        ns.n[i] = (int)(16.0 * pow(g, (double)i));
        long long np1 = ns.n[i] + 1;
        if (np1 * np1 * np1 <= TSIZE) ns.densemask |= (1u << i);
    }

    size_t wsNeed = (size_t)NLEVEL * (size_t)B * 4;   // fp16x2 per (level,point)
    if (ws_size >= wsNeed && d_ws != nullptr && (B & 31) == 0) {
        unsigned* ws = (unsigned*)d_ws;
        int gridA = (B + CHUNK - 1) / CHUNK;          // 512 at B=2M: 2 blocks/CU
        nerf_encode<<<gridA, 1024, 0, stream>>>(x, embed, ws, B, ns);
        nerf_mlp<<<2048, 256, 0, stream>>>(x, ws,
            dW0, db0, dW1, db1, cW0, cb0, cW1, cb1, cW2, cb2, out, B);
    } else {
        nerf_fused<<<2048, 256, 0, stream>>>(x, embed,
            dW0, db0, dW1, db1, cW0, cb0, cW1, cb1, cW2, cb2, out, B, ns);
    }
}

// Round 7
// 284.331 us; speedup vs baseline: 3.7400x; 1.1076x over previous
//
#include <hip/hip_runtime.h>
#include <math.h>

#define NLEVEL 16
#define TSIZE 16384
#define ESTRIDE 32768   // encode: 32 slices x 1024 threads

using half4 = __attribute__((ext_vector_type(4))) _Float16;
using f32x4 = __attribute__((ext_vector_type(4))) float;
using f32x2 = __attribute__((ext_vector_type(2))) float;
using u32x2 = __attribute__((ext_vector_type(2))) unsigned;
typedef __fp16 hv2 __attribute__((ext_vector_type(2)));

struct NsParam { int n[NLEVEL]; unsigned densemask; };

union Frag { half4 v; int i[2]; };
union Hu { unsigned u; hv2 h; };

// A-fragment for mfma_f32_16x16x16f16 of W^T (W row-major [K][N] fp32):
// lane (pt=lane&15, q=lane>>4) holds A[m=out][k=k0+4q+j], j=0..3.
__device__ __forceinline__ Frag load_wfrag(const float* __restrict__ W, int ldn,
                                           int k0, int q, int out,
                                           int kmax, int omax) {
    Frag f;
    #pragma unroll
    for (int j = 0; j < 4; ++j) {
        int k = k0 + 4 * q + j;
        float v = (k < kmax && out < omax) ? W[k * ldn + out] : 0.0f;
        f.v[j] = (_Float16)v;
    }
    return f;
}

__device__ __forceinline__ f32x4 mfma16(const Frag& a, const Frag& b, f32x4 c) {
    return __builtin_amdgcn_mfma_f32_16x16x16f16(a.v, b.v, c, 0, 0, 0);
}

// relu + cvt: C-tile f32x4 -> B-fragment half4 (layouts match for K=16!)
__device__ __forceinline__ Frag actpack(f32x4 a) {
    Frag f;
    #pragma unroll
    for (int j = 0; j < 4; ++j) f.v[j] = (_Float16)fmaxf(a[j], 0.0f);
    return f;
}

__device__ __forceinline__ float sigmoidf(float x) {
    return 1.0f / (1.0f + expf(-x));
}

// q-select among 4 values (q = lane>>4)
__device__ __forceinline__ int qsel(int q, int a, int b, int c, int d) {
    return (q & 2) ? ((q & 1) ? d : c) : ((q & 1) ? b : a);
}

// packed f32x2 -> fp16x2 (RTZ; staging the LDS table copy)
__device__ __forceinline__ unsigned pkrtz(float a, float b) {
    union { hv2 h; unsigned u; } r;
    r.h = __builtin_amdgcn_cvt_pkrtz(a, b);
    return r.u;
}

__device__ __forceinline__ hv2 splath(float w) {
    Hu r; r.u = pkrtz(w, w); return r.h;
}

// packed-fp16 lerp: a + w*(b-a)
__device__ __forceinline__ hv2 hlerp(hv2 a, hv2 b, hv2 w) {
    return (hv2)((b - a) * w + a);
}

// ============================================================================
// Phase A: hash-grid encode with LEVEL-PERSISTENT blocks.
// Round-7 delta: 512 blocks = 16 levels x 32 point-slices. Each block stages
// its level's fp16 table into LDS ONCE (was 16x per block: saves ~41K LDS-
// write cycles/CU, 31 of 32 __syncthreads, and 15/16 of the embed L2 reads),
// then streams 64 points/thread through it with chunked coord prefetch.
// ws becomes 16 per-level u32 planes (coalesced wave stores).
// ============================================================================

// Compute one point's 8 table indices and ISSUE the 8 LDS gathers.
__device__ __forceinline__ void gather_issue(
    const unsigned* __restrict__ tab,
    float cxp, float cyp, float czp,
    float fn, int np1, int np1sq, int dense,
    unsigned fe[8], float& w0, float& w1, float& w2)
{
    float xl0 = cxp * fn, xl1 = cyp * fn, xl2 = czp * fn;
    float f0 = floorf(xl0), f1 = floorf(xl1), f2 = floorf(xl2);
    int i0 = (int)f0, i1 = (int)f1, i2 = (int)f2;
    w0 = xl0 - f0; w1 = xl1 - f1; w2 = xl2 - f2;
    if (dense) {   // block-uniform branch now (levels 0,1 only)
        int d000 = i0 * np1sq + i1 * np1 + i2;
        #pragma unroll
        for (int c = 0; c < 8; ++c) {
            int o0 = (c >> 2) & 1, o1 = (c >> 1) & 1, o2 = c & 1;
            fe[c] = tab[d000 + (o0 ? np1sq : 0) + (o1 ? np1 : 0) + o2];
        }
    } else {
        unsigned hx0 = (unsigned)i0, hx1 = hx0 + 1u;
        unsigned hy0 = (unsigned)i1 * 2654435761u, hy1 = hy0 + 2654435761u;
        unsigned hz0 = (unsigned)i2 * 805459861u,  hz1 = hz0 + 805459861u;
        #pragma unroll
        for (int c = 0; c < 8; ++c) {
            int o0 = (c >> 2) & 1, o1 = (c >> 1) & 1, o2 = c & 1;
            unsigned h = (o0 ? hx1 : hx0) ^ (o1 ? hy1 : hy0) ^ (o2 ? hz1 : hz0);
            fe[c] = tab[h & (TSIZE - 1)];
        }
    }
}

// fp16 trilinear tree-lerp over the 8 gathered corners -> fp16x2 feature pair
__device__ __forceinline__ unsigned interp_tree(
    const unsigned fe[8], float w0, float w1, float w2)
{
    hv2 W0 = splath(w0), W1 = splath(w1), W2 = splath(w2);
    Hu a, b;
    a.u = fe[0]; b.u = fe[1]; hv2 g00 = hlerp(a.h, b.h, W2);
    a.u = fe[2]; b.u = fe[3]; hv2 g01 = hlerp(a.h, b.h, W2);
    a.u = fe[4]; b.u = fe[5]; hv2 g10 = hlerp(a.h, b.h, W2);
    a.u = fe[6]; b.u = fe[7]; hv2 g11 = hlerp(a.h, b.h, W2);
    hv2 gy0 = hlerp(g00, g01, W1);
    hv2 gy1 = hlerp(g10, g11, W1);
    Hu r; r.h = hlerp(gy0, gy1, W0);
    return r.u;
}

// load+clamp 4 chunk coords (indices clamped so overrun prefetch is safe)
__device__ __forceinline__ void loadc4(
    const float* __restrict__ x, int g0, int chunk, int B,
    float cx[4], float cy[4], float cz[4])
{
    #pragma unroll
    for (int p = 0; p < 4; ++p) {
        int idx = g0 + (chunk * 4 + p) * ESTRIDE;
        idx = (idx < B) ? idx : (B - 1);
        const float* xp = x + (size_t)idx * 6;
        f32x2 a = *(const f32x2*)xp;
        float pz = xp[2];
        cx[p] = fminf(fmaxf((a.x + 5.0f) / 10.0f, 0.0f), 0.999999f);
        cy[p] = fminf(fmaxf((a.y + 5.0f) / 10.0f, 0.0f), 0.999999f);
        cz[p] = fminf(fmaxf((pz  + 5.0f) / 10.0f, 0.0f), 0.999999f);
    }
}

// gather/interp pipeline over one 4-point chunk (1-ahead LDS pipeline)
__device__ __forceinline__ void enc_chunk(
    const unsigned* __restrict__ tab, unsigned* __restrict__ wplane,
    int g0, int chunk, int B,
    const float cx[4], const float cy[4], const float cz[4],
    float fn, int np1, int np1sq, int dense)
{
    unsigned fe[2][8];
    float w0s[2], w1s[2], w2s[2];
    gather_issue(tab, cx[0], cy[0], cz[0], fn, np1, np1sq, dense,
                 fe[0], w0s[0], w1s[0], w2s[0]);
    #pragma unroll
    for (int p = 0; p < 4; ++p) {
        if (p + 1 < 4)
            gather_issue(tab, cx[p + 1], cy[p + 1], cz[p + 1],
                         fn, np1, np1sq, dense,
                         fe[(p + 1) & 1], w0s[(p + 1) & 1],
                         w1s[(p + 1) & 1], w2s[(p + 1) & 1]);
        unsigned pk = interp_tree(fe[p & 1], w0s[p & 1], w1s[p & 1], w2s[p & 1]);
        int idx = g0 + (chunk * 4 + p) * ESTRIDE;
        if (idx < B) wplane[idx] = pk;
    }
}

__global__ __launch_bounds__(1024, 8) void nerf_encode(
    const float* __restrict__ x,
    const float* __restrict__ embed,
    unsigned* __restrict__ ws, int B, NsParam ns)
{
    __shared__ unsigned tab[TSIZE];   // fp16x2 entries, 64 KB -> 2 blocks/CU
    const int tid = threadIdx.x;
    const int l = blockIdx.x & 15;        // level
    const int slice = blockIdx.x >> 4;    // 0..31

    // stage this level's fp16 table ONCE
    {
        const f32x4* src = (const f32x4*)(embed + (size_t)l * (TSIZE * 2));
        #pragma unroll
        for (int j = 0; j < 8; ++j) {
            f32x4 v = src[tid + 1024 * j];
            u32x2 pk;
            pk.x = pkrtz(v.x, v.y);
            pk.y = pkrtz(v.z, v.w);
            *(u32x2*)(tab + 2 * (tid + 1024 * j)) = pk;
        }
    }
    __syncthreads();

    const int n = ns.n[l];
    const float fn = (float)n;
    const int np1 = n + 1, np1sq = np1 * np1;
    const int dense = (ns.densemask >> l) & 1;
    unsigned* __restrict__ wplane = ws + (size_t)l * B;

    const int g0 = slice * 1024 + tid;    // 0..32767
    const int nIter = (B + ESTRIDE - 1) / ESTRIDE;   // points per thread (64)
    const int NC = (nIter + 3) >> 2;                 // 4-pt chunks (16)

    // chunked coord prefetch: chunk c+1's 8 VMEM loads are in flight for the
    // whole ~600cy of chunk c's gathers+interp -> L3 latency hidden.
    float cxA[4], cyA[4], czA[4], cxB[4], cyB[4], czB[4];
    loadc4(x, g0, 0, B, cxA, cyA, czA);
    for (int c = 0; c < NC; c += 2) {
        loadc4(x, g0, c + 1, B, cxB, cyB, czB);
        enc_chunk(tab, wplane, g0, c, B, cxA, cyA, czA, fn, np1, np1sq, dense);
        loadc4(x, g0, c + 2, B, cxA, cyA, czA);
        if (c + 1 < NC)
            enc_chunk(tab, wplane, g0, c + 1, B, cxB, cyB, czB,
                      fn, np1, np1sq, dense);
    }
}

// ============================================================================
// Phase B: MFMA MLP, 32 points per wave-iteration (two independent chains).
// Round-7 delta: cW0/cW1 weight frags + ALL biases moved to LDS (~103 VGPR
// freed; LDS reads use lgkmcnt so they cannot re-trigger the vmcnt-ordering
// stall) + __launch_bounds__(256,4) forcing VGPR<=128 -> 4 waves/SIMD
// (was ~2 at ~220 VGPR: occupancy was the r6 mlp stall theory).
// Per-iteration opaque lane index defeats LICM re-hoisting LDS reads.
// ============================================================================
struct Pre { Frag f0[2], f1[2]; float vx[2], vy[2], vz[2]; };

__device__ __forceinline__ void prefetch_tile(
    const unsigned* __restrict__ ws, int B, int q,
    const float* __restrict__ x, int tile32, int pt, Pre& P)
{
    const unsigned* pl0 = ws + (size_t)(2 * q) * B;
    const unsigned* pl1 = ws + (size_t)(2 * q + 1) * B;
    const unsigned* pl2 = ws + (size_t)(8 + 2 * q) * B;
    const unsigned* pl3 = ws + (size_t)(9 + 2 * q) * B;
    #pragma unroll
    for (int g = 0; g < 2; ++g) {
        int ptg = tile32 * 32 + g * 16 + pt;
        P.f0[g].i[0] = (int)__builtin_nontemporal_load(pl0 + ptg);
        P.f0[g].i[1] = (int)__builtin_nontemporal_load(pl1 + ptg);
        P.f1[g].i[0] = (int)__builtin_nontemporal_load(pl2 + ptg);
        P.f1[g].i[1] = (int)__builtin_nontemporal_load(pl3 + ptg);
        const float* xp = x + (size_t)ptg * 6;
        P.vx[g] = xp[3];
        f32x2 v45 = *(const f32x2*)(xp + 4);
        P.vy[g] = v45.x; P.vz[g] = v45.y;
    }
}

__global__ __launch_bounds__(256, 4) void nerf_mlp(
    const float* __restrict__ x,
    const unsigned* __restrict__ ws,
    const float* __restrict__ dW0, const float* __restrict__ db0,
    const float* __restrict__ dW1, const float* __restrict__ db1,
    const float* __restrict__ cW0, const float* __restrict__ cb0,
    const float* __restrict__ cW1, const float* __restrict__ cb1,
    const float* __restrict__ cW2, const float* __restrict__ cb2,
    float* __restrict__ out, int B)
{
    const int lane = threadIdx.x & 63;
    const int pt = lane & 15;
    const int q  = lane >> 4;
    const int tid = threadIdx.x;
    const int wavesPerBlock = blockDim.x >> 6;
    const int waveId = blockIdx.x * wavesPerBlock + (threadIdx.x >> 6);
    const int waveStride = gridDim.x * wavesPerBlock;
    const int numT = B >> 5;   // 32-pt tiles

    // LDS-resident: cW0 (8 frags x 64 lanes), cW1 (16 x 64), biases
    __shared__ Frag wldsC0[8][64];    // 4 KB
    __shared__ Frag wldsC1[16][64];   // 8 KB
    __shared__ f32x4 blds[14][4];     // 896 B
    for (int e = tid; e < 8 * 64; e += 256) {
        int f = e >> 6, ln = e & 63;
        wldsC0[f][ln] = load_wfrag(cW0, 64, 16 * (f & 1), ln >> 4,
                                   16 * (f >> 1) + (ln & 15), 19, 64);
    }
    for (int e = tid; e < 16 * 64; e += 256) {
        int f = e >> 6, ln = e & 63;
        wldsC1[f][ln] = load_wfrag(cW1, 64, 16 * (f & 3), ln >> 4,
                                   16 * (f >> 2) + (ln & 15), 64, 64);
    }
    if (tid < 56) {
        int f = tid >> 2, qq = tid & 3;
        f32x4 v;
        if (f < 4)       v = *(const f32x4*)(db0 + 16 * f + 4 * qq);
        else if (f == 4) v = *(const f32x4*)(db1 + 4 * qq);
        else if (f < 9)  v = *(const f32x4*)(cb0 + 16 * (f - 5) + 4 * qq);
        else if (f < 13) v = *(const f32x4*)(cb1 + 16 * (f - 9) + 4 * qq);
        else {
            v[0] = (qq == 0) ? cb2[0] : 0.0f;
            v[1] = (qq == 0) ? cb2[1] : 0.0f;
            v[2] = (qq == 0) ? cb2[2] : 0.0f;
            v[3] = 0.0f;
        }
        blds[f][qq] = v;
    }

    // VGPR-resident weights: dW0 (8), dW1 (4), cW2 (4) frags = 32 VGPRs
    Frag wdW0[4][2], wdW1[4], wcW2[4];
    #pragma unroll
    for (int t = 0; t < 4; ++t)
        #pragma unroll
        for (int c = 0; c < 2; ++c)
            wdW0[t][c] = load_wfrag(dW0, 64, 16 * c, q, 16 * t + pt, 32, 64);
    #pragma unroll
    for (int c = 0; c < 4; ++c)
        wdW1[c] = load_wfrag(dW1, 16, 16 * c, q, pt, 64, 16);
    #pragma unroll
    for (int c = 0; c < 4; ++c)
        wcW2[c] = load_wfrag(cW2, 3, 16 * c, q, pt, 64, 3);

    __syncthreads();

    int tile = waveId;
    if (tile >= numT) return;

    Pre P;
    prefetch_tile(ws, B, q, x, tile, pt, P);

    for (;;) {
        int next = tile + waveStride;
        bool hasNext = next < numT;

        // consume prefetched registers (waits on loads issued 1 iter ago)
        Frag bf0[2] = { P.f0[0], P.f0[1] };
        Frag bf1[2] = { P.f1[0], P.f1[1] };
        float vx[2] = { P.vx[0], P.vx[1] };
        float vy[2] = { P.vy[0], P.vy[1] };
        float vz[2] = { P.vz[0], P.vz[1] };
        const int ptbase = tile * 32;

        if (hasNext) prefetch_tile(ws, B, q, x, next, pt, P);

        // fresh opaque indices each iteration: stops LICM hoisting the
        // loop-invariant LDS reads back into permanently-live VGPRs.
        int wl = lane, wq = q;
        asm("" : "+v"(wl));
        asm("" : "+v"(wq));

        __builtin_amdgcn_s_setprio(1);

        // ---- L0: h64 = dW0^T @ feats (4 out-tiles, K=32) x 2 chains ----
        f32x4 acc[2][4];
        #pragma unroll
        for (int t = 0; t < 4; ++t) {
            f32x4 b = blds[t][wq];
            #pragma unroll
            for (int g = 0; g < 2; ++g) {
                f32x4 a = b;
                a = mfma16(wdW0[t][0], bf0[g], a);
                a = mfma16(wdW0[t][1], bf1[g], a);
                acc[g][t] = a;
            }
        }
        Frag bh[2][4];
        #pragma unroll
        for (int c = 0; c < 4; ++c)
            #pragma unroll
            for (int g = 0; g < 2; ++g) bh[g][c] = actpack(acc[g][c]);

        // ---- L1: h16 = dW1^T @ relu(h64) (1 tile, K=64) ----
        f32x4 bl1 = blds[4][wq];
        f32x4 h[2] = { bl1, bl1 };
        #pragma unroll
        for (int c = 0; c < 4; ++c)
            #pragma unroll
            for (int g = 0; g < 2; ++g) h[g] = mfma16(wdW1[c], bh[g][c], h[g]);

        float dens[2];
        Frag bcin0[2], bcin1[2];
        #pragma unroll
        for (int g = 0; g < 2; ++g) {
            dens[g] = sigmoidf(h[g][0]);        // row 0 lives at q==0, reg 0
            float a0v = (q == 0) ? dens[g] : fmaxf(h[g][0], 0.0f);
            bcin0[g].v[0] = (_Float16)a0v;
            bcin0[g].v[1] = (_Float16)fmaxf(h[g][1], 0.0f);
            bcin0[g].v[2] = (_Float16)fmaxf(h[g][2], 0.0f);
            bcin0[g].v[3] = (_Float16)fmaxf(h[g][3], 0.0f);
            // k=16+4q+j: q==0 holds k16..19 = (vx,vy,vz,0) of its own point
            bcin1[g].v[0] = (_Float16)((q == 0) ? vx[g] : 0.0f);
            bcin1[g].v[1] = (_Float16)((q == 0) ? vy[g] : 0.0f);
            bcin1[g].v[2] = (_Float16)((q == 0) ? vz[g] : 0.0f);
            bcin1[g].v[3] = (_Float16)0.0f;
        }

        // ---- L2: c1 = cW0^T @ cin (4 out-tiles, K=19 padded to 32) ----
        #pragma unroll
        for (int t = 0; t < 4; ++t) {
            f32x4 b = blds[5 + t][wq];
            Frag w0f = wldsC0[2 * t + 0][wl];
            Frag w1f = wldsC0[2 * t + 1][wl];
            #pragma unroll
            for (int g = 0; g < 2; ++g) {
                f32x4 a = b;
                a = mfma16(w0f, bcin0[g], a);
                a = mfma16(w1f, bcin1[g], a);
                acc[g][t] = a;
            }
        }
        Frag bc[2][4];
        #pragma unroll
        for (int c = 0; c < 4; ++c)
            #pragma unroll
            for (int g = 0; g < 2; ++g) bc[g][c] = actpack(acc[g][c]);

        // ---- L3: c2 = cW1^T @ relu(c1) (4 out-tiles, K=64) ----
        #pragma unroll
        for (int t = 0; t < 4; ++t) {
            f32x4 b = blds[9 + t][wq];
            #pragma unroll
            for (int g = 0; g < 2; ++g) acc[g][t] = b;
            #pragma unroll
            for (int c = 0; c < 4; ++c) {
                Frag wf = wldsC1[4 * t + c][wl];
                #pragma unroll
                for (int g = 0; g < 2; ++g)
                    acc[g][t] = mfma16(wf, bc[g][c], acc[g][t]);
            }
        }
        Frag bd[2][4];
        #pragma unroll
        for (int c = 0; c < 4; ++c)
            #pragma unroll
            for (int g = 0; g < 2; ++g) bd[g][c] = actpack(acc[g][c]);

        // ---- L4: col = cW2^T @ relu(c2) (rows 0..2, K=64) ----
        f32x4 bl4 = blds[13][wq];
        f32x4 fo[2] = { bl4, bl4 };
        #pragma unroll
        for (int c = 0; c < 4; ++c)
            #pragma unroll
            for (int g = 0; g < 2; ++g) fo[g] = mfma16(wcW2[c], bd[g][c], fo[g]);

        __builtin_amdgcn_s_setprio(0);

        if (q == 0) {
            #pragma unroll
            for (int g = 0; g < 2; ++g) {
                f32x4 o;
                o[0] = dens[g];
                o[1] = sigmoidf(fo[g][0]);
                o[2] = sigmoidf(fo[g][1]);
                o[3] = sigmoidf(fo[g][2]);
                __builtin_nontemporal_store(o,
                    (f32x4*)(out + (size_t)(ptbase + g * 16 + pt) * 4));
            }
        }

        if (!hasNext) break;
        tile = next;
    }
}

// ============================================================================
// Fallback: fused single kernel if ws_size is insufficient (unchanged).
// ============================================================================
__device__ __forceinline__ void opaque(const float*& p) {
    asm("" : "+v"(p));
}

__device__ __forceinline__ void enc_issue(
    float px, float py, float pz,
    const float fn_[4], const float* const eb_[4],
    const int np1_[4], const int np1sq_[4], const bool dense_[4],
    f32x2 fe[4][8], float w_[4][3])
{
    float cx = fminf(fmaxf((px + 5.0f) / 10.0f, 0.0f), 0.999999f);
    float cy = fminf(fmaxf((py + 5.0f) / 10.0f, 0.0f), 0.999999f);
    float cz = fminf(fmaxf((pz + 5.0f) / 10.0f, 0.0f), 0.999999f);

    #pragma unroll
    for (int d = 0; d < 4; ++d) {
        float fn = fn_[d];
        float xl0 = cx * fn, xl1 = cy * fn, xl2 = cz * fn;
        float f0 = floorf(xl0), f1 = floorf(xl1), f2 = floorf(xl2);
        int i0 = (int)f0, i1 = (int)f1, i2 = (int)f2;
        w_[d][0] = xl0 - f0; w_[d][1] = xl1 - f1; w_[d][2] = xl2 - f2;

        unsigned hx0 = (unsigned)i0, hx1 = hx0 + 1u;
        unsigned hy0 = (unsigned)i1 * 2654435761u, hy1 = hy0 + 2654435761u;
        unsigned hz0 = (unsigned)i2 * 805459861u,  hz1 = hz0 + 805459861u;
        int dx0 = 0, dx1 = 0, dy0 = 0, dy1 = 0;
        if (d < 2) {
            dx0 = i0 * np1sq_[d]; dx1 = dx0 + np1sq_[d];
            dy0 = i1 * np1_[d];   dy1 = dy0 + np1_[d];
        }
        #pragma unroll
        for (int c = 0; c < 8; ++c) {
            int o0 = (c >> 2) & 1, o1 = (c >> 1) & 1, o2 = c & 1;
            unsigned h = (o0 ? hx1 : hx0) ^ (o1 ? hy1 : hy0) ^ (o2 ? hz1 : hz0);
            int ind = (int)(h & (TSIZE - 1));
            if (d < 2) {
                int di = (o0 ? dx1 : dx0) + (o1 ? dy1 : dy0) + i2 + o2;
                ind = dense_[d] ? di : ind;
            }
            fe[d][c] = *(const f32x2*)(eb_[d] + (size_t)ind * 2);
        }
    }
}

__global__ __launch_bounds__(256) void nerf_fused(
    const float* __restrict__ x,
    const float* __restrict__ embed,
    const float* __restrict__ dW0, const float* __restrict__ db0,
    const float* __restrict__ dW1, const float* __restrict__ db1,
    const float* __restrict__ cW0, const float* __restrict__ cb0,
    const float* __restrict__ cW1, const float* __restrict__ cb1,
    const float* __restrict__ cW2, const float* __restrict__ cb2,
    float* __restrict__ out, int B, NsParam ns)
{
    const int lane = threadIdx.x & 63;
    const int pt = lane & 15;
    const int q  = lane >> 4;
    const int wavesPerBlock = blockDim.x >> 6;
    const int waveId = blockIdx.x * wavesPerBlock + (threadIdx.x >> 6);
    const int waveStride = gridDim.x * wavesPerBlock;
    const int numTiles = B >> 4;

    Frag wdW0[4][2], wdW1[4], wcW0[4][2], wcW1[4][4], wcW2[4];
    #pragma unroll
    for (int t = 0; t < 4; ++t)
        #pragma unroll
        for (int c = 0; c < 2; ++c)
            wdW0[t][c] = load_wfrag(dW0, 64, 16 * c, q, 16 * t + pt, 32, 64);
    #pragma unroll
    for (int c = 0; c < 4; ++c)
        wdW1[c] = load_wfrag(dW1, 16, 16 * c, q, pt, 64, 16);
    #pragma unroll
    for (int t = 0; t < 4; ++t)
        #pragma unroll
        for (int c = 0; c < 2; ++c)
            wcW0[t][c] = load_wfrag(cW0, 64, 16 * c, q, 16 * t + pt, 19, 64);
    #pragma unroll
    for (int t = 0; t < 4; ++t)
        #pragma unroll
        for (int c = 0; c < 4; ++c)
            wcW1[t][c] = load_wfrag(cW1, 64, 16 * c, q, 16 * t + pt, 64, 64);
    #pragma unroll
    for (int c = 0; c < 4; ++c)
        wcW2[c] = load_wfrag(cW2, 3, 16 * c, q, pt, 64, 3);

    float fn_[4];
    const float* eb_[4];
    int np1_[4], np1sq_[4];
    bool dense_[4];
    #pragma unroll
    for (int d = 0; d < 4; ++d) {
        int base = (d < 2) ? (d) : (8 + (d - 2));
        int lvl = base + 2 * q;
        int n = qsel(q, ns.n[base], ns.n[base + 2], ns.n[base + 4], ns.n[base + 6]);
        fn_[d] = (float)n;
        np1_[d] = n + 1;
        np1sq_[d] = (n + 1) * (n + 1);
        dense_[d] = (ns.densemask >> lvl) & 1u;
        eb_[d] = embed + (size_t)lvl * (TSIZE * 2);
    }

    for (int tile = waveId; tile < numTiles; tile += waveStride) {
        const int ptg = tile * 16 + pt;
        const float* xp = x + (size_t)ptg * 6;
        f32x2 x01 = *(const f32x2*)(xp);
        f32x2 x23 = *(const f32x2*)(xp + 2);
        f32x2 x45 = *(const f32x2*)(xp + 4);
        float vx = x23.y, vy = x45.x, vz = x45.y;

        f32x2 fe[4][8];
        float w_[4][3];
        enc_issue(x01.x, x01.y, x23.x, fn_, eb_, np1_, np1sq_, dense_, fe, w_);

        Frag bf0, bf1;
        #pragma unroll
        for (int d = 0; d < 4; ++d) {
            float w0 = w_[d][0], w1 = w_[d][1], w2 = w_[d][2];
            float u0 = 1.0f - w0, u1 = 1.0f - w1, u2 = 1.0f - w2;
            float wxy[4] = { u0 * u1, u0 * w1, w0 * u1, w0 * w1 };
            float a0 = 0.0f, a1 = 0.0f;
            #pragma unroll
            for (int c = 0; c < 8; ++c) {
                float ww = wxy[c >> 1] * ((c & 1) ? w2 : u2);
                a0 = fmaf(fe[d][c].x, ww, a0);
                a1 = fmaf(fe[d][c].y, ww, a1);
            }
            if (d == 0)      { bf0.v[0] = (_Float16)a0; bf0.v[1] = (_Float16)a1; }
            else if (d == 1) { bf0.v[2] = (_Float16)a0; bf0.v[3] = (_Float16)a1; }
            else if (d == 2) { bf1.v[0] = (_Float16)a0; bf1.v[1] = (_Float16)a1; }
            else             { bf1.v[2] = (_Float16)a0; bf1.v[3] = (_Float16)a1; }
        }

        const float* db0o = db0; const float* db1o = db1;
        const float* cb0o = cb0; const float* cb1o = cb1;
        const float* cb2o = cb2;
        opaque(db0o); opaque(db1o); opaque(cb0o); opaque(cb1o); opaque(cb2o);

        f32x4 acc[4];
        #pragma unroll
        for (int t = 0; t < 4; ++t) {
            acc[t] = *(const f32x4*)(db0o + 16 * t + 4 * q);
            acc[t] = mfma16(wdW0[t][0], bf0, acc[t]);
            acc[t] = mfma16(wdW0[t][1], bf1, acc[t]);
        }
        Frag bh[4];
        #pragma unroll
        for (int c = 0; c < 4; ++c) bh[c] = actpack(acc[c]);

        f32x4 h = *(const f32x4*)(db1o + 4 * q);
        #pragma unroll
        for (int c = 0; c < 4; ++c) h = mfma16(wdW1[c], bh[c], h);

        float dens = sigmoidf(h[0]);
        Frag bcin0, bcin1;
        {
            float a0v = (q == 0) ? dens : fmaxf(h[0], 0.0f);
            bcin0.v[0] = (_Float16)a0v;
            bcin0.v[1] = (_Float16)fmaxf(h[1], 0.0f);
            bcin0.v[2] = (_Float16)fmaxf(h[2], 0.0f);
            bcin0.v[3] = (_Float16)fmaxf(h[3], 0.0f);
            bcin1.v[0] = (_Float16)((q == 0) ? vx : 0.0f);
            bcin1.v[1] = (_Float16)((q == 0) ? vy : 0.0f);
            bcin1.v[2] = (_Float16)((q == 0) ? vz : 0.0f);
            bcin1.v[3] = (_Float16)0.0f;
        }

        #pragma unroll
        for (int t = 0; t < 4; ++t) {
            acc[t] = *(const f32x4*)(cb0o + 16 * t + 4 * q);
            acc[t] = mfma16(wcW0[t][0], bcin0, acc[t]);
            acc[t] = mfma16(wcW0[t][1], bcin1, acc[t]);
        }
        Frag bc[4];
        #pragma unroll
        for (int c = 0; c < 4; ++c) bc[c] = actpack(acc[c]);

        #pragma unroll
        for (int t = 0; t < 4; ++t) {
            acc[t] = *(const f32x4*)(cb1o + 16 * t + 4 * q);
            #pragma unroll
            for (int c = 0; c < 4; ++c) acc[t] = mfma16(wcW1[t][c], bc[c], acc[t]);
        }
        Frag bd[4];
        #pragma unroll
        for (int c = 0; c < 4; ++c) bd[c] = actpack(acc[c]);

        float b0 = cb2o[0], b1 = cb2o[1], b2 = cb2o[2];
        f32x4 fo;
        fo[0] = (q == 0) ? b0 : 0.0f;
        fo[1] = (q == 0) ? b1 : 0.0f;
        fo[2] = (q == 0) ? b2 : 0.0f;
        fo[3] = 0.0f;
        #pragma unroll
        for (int c = 0; c < 4; ++c) fo = mfma16(wcW2[c], bd[c], fo);

        if (q == 0) {
            f32x4 o;
            o[0] = dens;
            o[1] = sigmoidf(fo[0]);
            o[2] = sigmoidf(fo[1]);
            o[3] = sigmoidf(fo[2]);
            *(f32x4*)(out + (size_t)ptg * 4) = o;
        }
    }
}

extern "C" void kernel_launch(void* const* d_in, const int* in_sizes, int n_in,
                              void* d_out, int out_size, void* d_ws, size_t ws_size,
                              hipStream_t stream) {
    const float* x    = (const float*)d_in[0];
    const float* embed= (const float*)d_in[1];
    const float* dW0  = (const float*)d_in[2];
    const float* db0  = (const float*)d_in[3];
    const float* dW1  = (const float*)d_in[4];
    const float* db1  = (const float*)d_in[5];
    const float* cW0  = (const float*)d_in[6];
    const float* cb0  = (const float*)d_in[7];
    const float* cW1  = (const float*)d_in[8];
    const float* cb1  = (const float*)d_in[9];
    const float* cW2  = (const float*)d_in[10];
    const float* cb2  = (const float*)d_in[11];
    float* out = (float*)d_out;

    int B = in_sizes[0] / 6;

    // Replicate numpy's NS computation bit-for-bit (same libm on this host).
    NsParam ns;
    double g = exp((log(512.0) - log(16.0)) / 15.0);
    ns.densemask = 0;
    for (int i = 0; i < NLEVEL; ++i) {
        ns.n[i] = (int)(16.0 * pow(g, (double)i));
        long long np1 = ns.n[i] + 1;
        if (np1 * np1 * np1 <= TSIZE) ns.densemask |= (1u << i);
    }

    size_t wsNeed = (size_t)NLEVEL * (size_t)B * 4;   // fp16x2 per (level,point)
    if (ws_size >= wsNeed && d_ws != nullptr && (B & 31) == 0 && B >= 32) {
        unsigned* ws = (unsigned*)d_ws;
        nerf_encode<<<512, 1024, 0, stream>>>(x, embed, ws, B, ns);
        nerf_mlp<<<2048, 256, 0, stream>>>(x, ws,
            dW0, db0, dW1, db1, cW0, cb0, cW1, cb1, cW2, cb2, out, B);
    } else {
        nerf_fused<<<2048, 256, 0, stream>>>(x, embed,
            dW0, db0, dW1, db1, cW0, cb0, cW1, cb1, cW2, cb2, out, B, ns);
    }
}